// Round 4
// baseline (501.033 us; speedup 1.0000x reference)
//
#include <hip/hip_runtime.h>
#include <math.h>

#define BB 4
#define SS 2048
#define DD 1024
#define HH 16
#define HDD 64
#define NN (BB*SS)            // 8192 rows
#define WINDOWF 604800.0f     // 7 days
#define LOG2E 1.44269504088896340736f
#define SCALE2 (0.125f * LOG2E)   // 1/sqrt(64) * log2(e): scores in log2 domain

typedef __attribute__((ext_vector_type(8))) short bf16x8;
typedef __attribute__((ext_vector_type(4))) short bf16x4;
typedef __attribute__((ext_vector_type(4))) short s16x4;
typedef __attribute__((ext_vector_type(4))) float f32x4;

__device__ __forceinline__ unsigned short f2b(float f) {
    unsigned int x = __float_as_uint(f);
    unsigned int r = x + 0x7FFFu + ((x >> 16) & 1u);
    return (unsigned short)(r >> 16);
}

__device__ __forceinline__ unsigned int cvt_pk_bf16(float lo, float hi) {
    unsigned int r;
    asm("v_cvt_pk_bf16_f32 %0, %1, %2" : "=v"(r) : "v"(lo), "v"(hi));
    return r;
}

// ---------------------------------------------------------------------------
// f32 -> bf16 (RTN), vectorized
// ---------------------------------------------------------------------------
__global__ __launch_bounds__(256)
void cvt_bf16(const float* __restrict__ src, unsigned short* __restrict__ dst, int n)
{
    int i = (blockIdx.x * 256 + threadIdx.x) * 4;
    if (i >= n) return;
    float4 v = *(const float4*)(src + i);
    s16x4 o;
    o[0] = (short)f2b(v.x); o[1] = (short)f2b(v.y);
    o[2] = (short)f2b(v.z); o[3] = (short)f2b(v.w);
    *(s16x4*)(dst + i) = o;
}

// ---------------------------------------------------------------------------
// bf16 MFMA GEMM: Y = (A @ Bw^T + bias) * alpha
// OUTMODE: 0 = f32 row-major, 1 = bf16 row-major,
//          2 = bf16 transposed Vt layout [b][channel][s] (channel = h*64+d)
// ---------------------------------------------------------------------------
template<int OUTMODE>
__global__ __launch_bounds__(256)
void gemm_bf16(const unsigned short* __restrict__ A,
               const unsigned short* __restrict__ Bw,
               const float* __restrict__ bias,
               void* __restrict__ Y, int M, int N, int K, float alpha)
{
    constexpr int BM = 128, BN = 128, BK = 32;
    constexpr int LDA = 40;                       // padded row, elems
    __shared__ unsigned short As[BM * LDA];
    __shared__ unsigned short Bs[BN * LDA];

    const int bm = blockIdx.x * BM;
    const int bn = blockIdx.y * BN;
    const int tid = threadIdx.x;
    const int wid = tid >> 6, l = tid & 63;
    const int wm = (wid >> 1) * 64, wn = (wid & 1) * 64;
    const int lr = l & 15, lg = l >> 4;

    f32x4 acc[4][4];
#pragma unroll
    for (int i = 0; i < 4; ++i)
#pragma unroll
        for (int j = 0; j < 4; ++j) acc[i][j] = (f32x4){0.f, 0.f, 0.f, 0.f};

    for (int k0 = 0; k0 < K; k0 += BK) {
        bf16x8 av[2], bv[2];
#pragma unroll
        for (int t = 0; t < 2; ++t) {
            int idx = t * 256 + tid;
            int r = idx >> 2, c = (idx & 3) * 8;
            av[t] = *(const bf16x8*)(A  + (size_t)(bm + r) * K + k0 + c);
            bv[t] = *(const bf16x8*)(Bw + (size_t)(bn + r) * K + k0 + c);
        }
        __syncthreads();
#pragma unroll
        for (int t = 0; t < 2; ++t) {
            int idx = t * 256 + tid;
            int r = idx >> 2, c = (idx & 3) * 8;
            *(bf16x8*)&As[r * LDA + c] = av[t];
            *(bf16x8*)&Bs[r * LDA + c] = bv[t];
        }
        __syncthreads();

        bf16x8 af[4], bf[4];
#pragma unroll
        for (int am = 0; am < 4; ++am)
            af[am] = *(const bf16x8*)&As[(wm + am * 16 + lr) * LDA + lg * 8];
#pragma unroll
        for (int nf = 0; nf < 4; ++nf)
            bf[nf] = *(const bf16x8*)&Bs[(wn + nf * 16 + lr) * LDA + lg * 8];
#pragma unroll
        for (int am = 0; am < 4; ++am)
#pragma unroll
            for (int nf = 0; nf < 4; ++nf)
                acc[am][nf] = __builtin_amdgcn_mfma_f32_16x16x32_bf16(
                    af[am], bf[nf], acc[am][nf], 0, 0, 0);
    }

    float bia[4];
#pragma unroll
    for (int nf = 0; nf < 4; ++nf) bia[nf] = bias[bn + wn + nf * 16 + lr];

#pragma unroll
    for (int am = 0; am < 4; ++am)
#pragma unroll
        for (int nf = 0; nf < 4; ++nf) {
            if (OUTMODE == 2) {
                // transposed Vt store: 4 consecutive s per lane, packed 8B
                int mbase = bm + wm + am * 16 + lg * 4;     // = b*SS + s_base
                int n = bn + wn + nf * 16 + lr;
                int bidx = mbase >> 11, sidx = mbase & (SS - 1);
                s16x4 o;
#pragma unroll
                for (int r = 0; r < 4; ++r)
                    o[r] = (short)f2b((acc[am][nf][r] + bia[nf]) * alpha);
                *(s16x4*)((unsigned short*)Y +
                          (((size_t)(bidx << 10) + n) << 11) + sidx) = o;
            } else {
#pragma unroll
                for (int r = 0; r < 4; ++r) {
                    float o = (acc[am][nf][r] + bia[nf]) * alpha;
                    size_t m = (size_t)(bm + wm + am * 16 + lg * 4 + r);
                    size_t n = (size_t)(bn + wn + nf * 16 + lr);
                    if (OUTMODE == 1) ((unsigned short*)Y)[m * N + n] = f2b(o);
                    else              ((float*)Y)[m * N + n] = o;
                }
            }
        }
}

// ---------------------------------------------------------------------------
// Per-query band bounds via binary search (timestamps sorted per sequence).
// Conservative by +/-1s slack; exact f32 mask applied inside attention tile.
// ---------------------------------------------------------------------------
__global__ __launch_bounds__(256)
void band_bounds(const float* __restrict__ ts, int* __restrict__ lo, int* __restrict__ hi)
{
    int idx = blockIdx.x * 256 + threadIdx.x;
    if (idx >= NN) return;
    int b = idx / SS, q = idx % SS;
    const float* t = ts + (size_t)b * SS;
    float tq = t[q];
    float lot = tq - WINDOWF - 1.0f;
    float hit = tq + WINDOWF + 1.0f;
    int l = 0, r = q;
    while (l < r) { int m = (l + r) >> 1; if (t[m] < lot) l = m + 1; else r = m; }
    lo[idx] = l;
    int l2 = q, r2 = SS - 1;
    while (l2 < r2) { int m = (l2 + r2 + 1) >> 1; if (t[m] > hit) r2 = m - 1; else l2 = m; }
    hi[idx] = l2;
}

// ---------------------------------------------------------------------------
// MFMA flash attention, swapped-operand, LDS-free, barrier-free.
// Block = 256 thr = 4 independent waves; wave owns 16 q rows (q = q0w + lane&15).
// S^T = mfma(K,Q) puts each q's keys lane-local: softmax = local reduce + 2 shfl.
// PV uses the PROVEN mfma_f32_16x16x32_bf16 with a permuted k-enumeration
// pi(c,lg,j) = (2c + (j>>2))*16 + lg*4 + (j&3), applied to BOTH operands:
// B-frag = the 4 cvt_pk words already in registers (zero cross-lane moves),
// A-frag = two contiguous 8B loads from global Vt (L2-resident).
// ---------------------------------------------------------------------------
__global__ __launch_bounds__(256, 4)
void attn_mfma(const unsigned short* __restrict__ Qb, const unsigned short* __restrict__ Kb,
               const unsigned short* __restrict__ Vt, const float* __restrict__ Tg,
               const int* __restrict__ lo, const int* __restrict__ hi,
               unsigned short* __restrict__ Ab)
{
    const int blk = blockIdx.x;
    const int qt = blk & 31, h = (blk >> 5) & 15, b = blk >> 9;
    const int tid = threadIdx.x;
    const int wid = tid >> 6, l = tid & 63;
    const int lr = l & 15, lg = l >> 4;
    const int q0w = qt * 64 + wid * 16;

    const size_t qrow = (size_t)(b * SS + q0w + lr);
    const bf16x8 qf0 = *(const bf16x8*)(Qb + qrow * DD + h * HDD + lg * 8);
    const bf16x8 qf1 = *(const bf16x8*)(Qb + qrow * DD + h * HDD + 32 + lg * 8);

    const float* tb = Tg + (size_t)b * SS;
    const float tq = tb[q0w + lr];
    const float tq_min = tb[q0w];          // uniform (sorted)
    const float tq_max = tb[q0w + 15];     // uniform

    const int t0 = lo[b * SS + q0w] >> 6;
    const int t1 = hi[b * SS + q0w + 15] >> 6;

    const unsigned short* Kbh = Kb + (size_t)b * SS * DD + h * HDD;
    const unsigned short* Vth = Vt + ((size_t)(b * 1024 + h * HDD)) * SS;

    float m_ = -1e30f, l_ = 0.f;
    f32x4 oaccT[4];
#pragma unroll
    for (int df = 0; df < 4; ++df) oaccT[df] = (f32x4){0.f, 0.f, 0.f, 0.f};

    for (int t = t0; t <= t1; ++t) {
        const int kk0 = t * 64;

        // S^T[key][q] (log2 domain: scale pre-folded into Q)
        f32x4 s[4];
#pragma unroll
        for (int kf = 0; kf < 4; ++kf) {
            const unsigned short* kp = Kbh + (size_t)(kk0 + kf * 16 + lr) * DD;
            bf16x8 ka0 = *(const bf16x8*)(kp + lg * 8);
            bf16x8 ka1 = *(const bf16x8*)(kp + 32 + lg * 8);
            f32x4 z = (f32x4){0.f, 0.f, 0.f, 0.f};
            z = __builtin_amdgcn_mfma_f32_16x16x32_bf16(ka0, qf0, z, 0, 0, 0);
            z = __builtin_amdgcn_mfma_f32_16x16x32_bf16(ka1, qf1, z, 0, 0, 0);
            s[kf] = z;
        }

        // exact mask only on boundary tiles (conservative uniform test, 4s margin)
        const bool needmask = !((tq_max - tb[kk0] <= WINDOWF - 4.0f) &&
                                (tb[kk0 + 63] - tq_min <= WINDOWF - 4.0f));
        if (needmask) {
#pragma unroll
            for (int kf = 0; kf < 4; ++kf) {
                float4 tk4 = *(const float4*)(tb + kk0 + kf * 16 + lg * 4);
                if (!(fabsf(tq - tk4.x) <= WINDOWF)) s[kf][0] = -INFINITY;
                if (!(fabsf(tq - tk4.y) <= WINDOWF)) s[kf][1] = -INFINITY;
                if (!(fabsf(tq - tk4.z) <= WINDOWF)) s[kf][2] = -INFINITY;
                if (!(fabsf(tq - tk4.w) <= WINDOWF)) s[kf][3] = -INFINITY;
            }
        }

        // online softmax: lane-local 16 keys, reduce across lg via 2 shuffles
        float mt = s[0][0];
#pragma unroll
        for (int kf = 0; kf < 4; ++kf)
#pragma unroll
            for (int r = 0; r < 4; ++r) mt = fmaxf(mt, s[kf][r]);
        mt = fmaxf(mt, __shfl_xor(mt, 16));
        mt = fmaxf(mt, __shfl_xor(mt, 32));
        const float mn = fmaxf(m_, mt);
        const float f_ = __builtin_amdgcn_exp2f(m_ - mn);
        float rs = 0.f;
#pragma unroll
        for (int kf = 0; kf < 4; ++kf)
#pragma unroll
            for (int r = 0; r < 4; ++r) {
                float p = __builtin_amdgcn_exp2f(s[kf][r] - mn);
                s[kf][r] = p;
                rs += p;
            }
        rs += __shfl_xor(rs, 16);
        rs += __shfl_xor(rs, 32);
        l_ = l_ * f_ + rs;
        m_ = mn;
#pragma unroll
        for (int df = 0; df < 4; ++df)
#pragma unroll
            for (int r = 0; r < 4; ++r) oaccT[df][r] *= f_;

        // P^T -> packed bf16 words (in-register, no LDS, no cross-lane)
        unsigned int pw[4][2];
#pragma unroll
        for (int kf = 0; kf < 4; ++kf) {
            pw[kf][0] = cvt_pk_bf16(s[kf][0], s[kf][1]);
            pw[kf][1] = cvt_pk_bf16(s[kf][2], s[kf][3]);
        }
        union { unsigned int u[4]; bf16x8 v; } pb[2];
#pragma unroll
        for (int c = 0; c < 2; ++c) {
            pb[c].u[0] = pw[2 * c][0];     pb[c].u[1] = pw[2 * c][1];
            pb[c].u[2] = pw[2 * c + 1][0]; pb[c].u[3] = pw[2 * c + 1][1];
        }

        // O^T += V^T . P^T  via 16x16x32 MFMA, permuted-k on both operands
#pragma unroll
        for (int df = 0; df < 4; ++df) {
            const unsigned short* vrow = Vth + (size_t)(df * 16 + lr) * SS + kk0 + lg * 4;
#pragma unroll
            for (int c = 0; c < 2; ++c) {
                union { bf16x4 h[2]; bf16x8 w; } va;
                va.h[0] = *(const bf16x4*)(vrow + (2 * c) * 16);
                va.h[1] = *(const bf16x4*)(vrow + (2 * c + 1) * 16);
                oaccT[df] = __builtin_amdgcn_mfma_f32_16x16x32_bf16(
                    va.w, pb[c].v, oaccT[df], 0, 0, 0);
            }
        }
    }

    // finalize: attended[q][d] = O^T / l, packed 8B stores
    const float inv = 1.f / l_;
#pragma unroll
    for (int df = 0; df < 4; ++df) {
        s16x4 o;
#pragma unroll
        for (int r = 0; r < 4; ++r) o[r] = (short)f2b(oaccT[df][r] * inv);
        *(s16x4*)(Ab + qrow * DD + h * HDD + df * 16 + lg * 4) = o;
    }
}

// ---------------------------------------------------------------------------
// change_scores[n] = out[n,:] . Wc + bc   (one wave per row)
// ---------------------------------------------------------------------------
__global__ __launch_bounds__(256)
void change_kernel(const float* __restrict__ out, const float* __restrict__ Wc,
                   const float* __restrict__ bc, float* __restrict__ cs)
{
    int row = blockIdx.x * 4 + (threadIdx.x >> 6);
    int lane = threadIdx.x & 63;
    const float* o = out + (size_t)row * DD;
    float sum = 0.f;
#pragma unroll
    for (int k = 0; k < DD / 256; ++k) {
        int c = lane * 4 + k * 256;
        float4 v = *(const float4*)(o + c);
        float4 w = *(const float4*)(Wc + c);
        sum += v.x * w.x + v.y * w.y + v.z * w.z + v.w * w.w;
    }
#pragma unroll
    for (int off = 1; off < 64; off <<= 1) sum += __shfl_xor(sum, off);
    if (lane == 0) cs[row] = sum + bc[0];
}

// ---------------------------------------------------------------------------
extern "C" void kernel_launch(void* const* d_in, const int* in_sizes, int n_in,
                              void* d_out, int out_size, void* d_ws, size_t ws_size,
                              hipStream_t stream)
{
    (void)in_sizes; (void)n_in; (void)out_size; (void)ws_size;
    const float* x  = (const float*)d_in[0];
    const float* ts = (const float*)d_in[1];
    const float* Wq = (const float*)d_in[2];
    const float* bq = (const float*)d_in[3];
    const float* Wk = (const float*)d_in[4];
    const float* bk = (const float*)d_in[5];
    const float* Wv = (const float*)d_in[6];
    const float* bv = (const float*)d_in[7];
    const float* Wo = (const float*)d_in[8];
    const float* bo = (const float*)d_in[9];
    const float* Wc = (const float*)d_in[10];
    const float* bc = (const float*)d_in[11];

    float* out = (float*)d_out;                 // [N*D] output, then [N] change scores

    unsigned short* xb  = (unsigned short*)d_ws;
    unsigned short* Qb  = xb  + (size_t)NN * DD;
    unsigned short* Kb2 = Qb  + (size_t)NN * DD;
    unsigned short* Vtb = Kb2 + (size_t)NN * DD;   // transposed [b][h*64+d][s]
    unsigned short* Abf = Vtb + (size_t)NN * DD;
    unsigned short* Wqb = Abf + (size_t)NN * DD;
    unsigned short* Wkb = Wqb + (size_t)DD * DD;
    unsigned short* Wvb = Wkb + (size_t)DD * DD;
    unsigned short* Wob = Wvb + (size_t)DD * DD;
    int* lo = (int*)(Wob + (size_t)DD * DD);
    int* hi = lo + NN;

    // converts
    cvt_bf16<<<(NN * DD / 4 + 255) / 256, 256, 0, stream>>>(x, xb, NN * DD);
    cvt_bf16<<<(DD * DD / 4 + 255) / 256, 256, 0, stream>>>(Wq, Wqb, DD * DD);
    cvt_bf16<<<(DD * DD / 4 + 255) / 256, 256, 0, stream>>>(Wk, Wkb, DD * DD);
    cvt_bf16<<<(DD * DD / 4 + 255) / 256, 256, 0, stream>>>(Wv, Wvb, DD * DD);
    cvt_bf16<<<(DD * DD / 4 + 255) / 256, 256, 0, stream>>>(Wo, Wob, DD * DD);

    dim3 g(NN / 128, DD / 128);
    gemm_bf16<1><<<g, 256, 0, stream>>>(xb, Wqb, bq, Qb,  NN, DD, DD, SCALE2);
    gemm_bf16<1><<<g, 256, 0, stream>>>(xb, Wkb, bk, Kb2, NN, DD, DD, 1.0f);
    gemm_bf16<2><<<g, 256, 0, stream>>>(xb, Wvb, bv, Vtb, NN, DD, DD, 1.0f);
    band_bounds<<<NN / 256, 256, 0, stream>>>(ts, lo, hi);
    attn_mfma<<<BB * HH * (SS / 64), 256, 0, stream>>>(Qb, Kb2, Vtb, ts, lo, hi, Abf);
    gemm_bf16<0><<<g, 256, 0, stream>>>(Abf, Wob, bo, out, NN, DD, DD, 1.0f);
    change_kernel<<<NN / 4, 256, 0, stream>>>(out, Wc, bc, out + (size_t)NN * DD);
}

// Round 5
// 387.157 us; speedup vs baseline: 1.2941x; 1.2941x over previous
//
#include <hip/hip_runtime.h>
#include <math.h>

#define BB 4
#define SS 2048
#define DD 1024
#define HH 16
#define HDD 64
#define NN (BB*SS)            // 8192 rows
#define WINDOWF 604800.0f     // 7 days
#define LOG2E 1.44269504088896340736f
#define SCALE2 (0.125f * LOG2E)   // 1/sqrt(64) * log2(e): scores in log2 domain

typedef __attribute__((ext_vector_type(8))) short bf16x8;
typedef __attribute__((ext_vector_type(4))) short bf16x4;
typedef __attribute__((ext_vector_type(4))) short s16x4;
typedef __attribute__((ext_vector_type(4))) float f32x4;

__device__ __forceinline__ unsigned short f2b(float f) {
    unsigned int x = __float_as_uint(f);
    unsigned int r = x + 0x7FFFu + ((x >> 16) & 1u);
    return (unsigned short)(r >> 16);
}

__device__ __forceinline__ unsigned int cvt_pk_bf16(float lo, float hi) {
    unsigned int r;
    asm("v_cvt_pk_bf16_f32 %0, %1, %2" : "=v"(r) : "v"(lo), "v"(hi));
    return r;
}

// ---------------------------------------------------------------------------
// f32 -> bf16 (RTN), vectorized
// ---------------------------------------------------------------------------
__global__ __launch_bounds__(256)
void cvt_bf16(const float* __restrict__ src, unsigned short* __restrict__ dst, int n)
{
    int i = (blockIdx.x * 256 + threadIdx.x) * 4;
    if (i >= n) return;
    float4 v = *(const float4*)(src + i);
    s16x4 o;
    o[0] = (short)f2b(v.x); o[1] = (short)f2b(v.y);
    o[2] = (short)f2b(v.z); o[3] = (short)f2b(v.w);
    *(s16x4*)(dst + i) = o;
}

// ---------------------------------------------------------------------------
// bf16 MFMA GEMM: Y = (A @ Bw^T + bias) * alpha
// OUTMODE: 0 = f32 row-major, 1 = bf16 row-major,
//          2 = bf16 transposed Vt layout [b][channel][s] (channel = h*64+d)
// ---------------------------------------------------------------------------
template<int OUTMODE>
__global__ __launch_bounds__(256)
void gemm_bf16(const unsigned short* __restrict__ A,
               const unsigned short* __restrict__ Bw,
               const float* __restrict__ bias,
               void* __restrict__ Y, int M, int N, int K, float alpha)
{
    constexpr int BM = 128, BN = 128, BK = 32;
    constexpr int LDA = 40;                       // padded row, elems
    __shared__ unsigned short As[BM * LDA];
    __shared__ unsigned short Bs[BN * LDA];

    const int bm = blockIdx.x * BM;
    const int bn = blockIdx.y * BN;
    const int tid = threadIdx.x;
    const int wid = tid >> 6, l = tid & 63;
    const int wm = (wid >> 1) * 64, wn = (wid & 1) * 64;
    const int lr = l & 15, lg = l >> 4;

    f32x4 acc[4][4];
#pragma unroll
    for (int i = 0; i < 4; ++i)
#pragma unroll
        for (int j = 0; j < 4; ++j) acc[i][j] = (f32x4){0.f, 0.f, 0.f, 0.f};

    for (int k0 = 0; k0 < K; k0 += BK) {
        bf16x8 av[2], bv[2];
#pragma unroll
        for (int t = 0; t < 2; ++t) {
            int idx = t * 256 + tid;
            int r = idx >> 2, c = (idx & 3) * 8;
            av[t] = *(const bf16x8*)(A  + (size_t)(bm + r) * K + k0 + c);
            bv[t] = *(const bf16x8*)(Bw + (size_t)(bn + r) * K + k0 + c);
        }
        __syncthreads();
#pragma unroll
        for (int t = 0; t < 2; ++t) {
            int idx = t * 256 + tid;
            int r = idx >> 2, c = (idx & 3) * 8;
            *(bf16x8*)&As[r * LDA + c] = av[t];
            *(bf16x8*)&Bs[r * LDA + c] = bv[t];
        }
        __syncthreads();

        bf16x8 af[4], bf[4];
#pragma unroll
        for (int am = 0; am < 4; ++am)
            af[am] = *(const bf16x8*)&As[(wm + am * 16 + lr) * LDA + lg * 8];
#pragma unroll
        for (int nf = 0; nf < 4; ++nf)
            bf[nf] = *(const bf16x8*)&Bs[(wn + nf * 16 + lr) * LDA + lg * 8];
#pragma unroll
        for (int am = 0; am < 4; ++am)
#pragma unroll
            for (int nf = 0; nf < 4; ++nf)
                acc[am][nf] = __builtin_amdgcn_mfma_f32_16x16x32_bf16(
                    af[am], bf[nf], acc[am][nf], 0, 0, 0);
    }

    float bia[4];
#pragma unroll
    for (int nf = 0; nf < 4; ++nf) bia[nf] = bias[bn + wn + nf * 16 + lr];

#pragma unroll
    for (int am = 0; am < 4; ++am)
#pragma unroll
        for (int nf = 0; nf < 4; ++nf) {
            if (OUTMODE == 2) {
                // transposed Vt store: 4 consecutive s per lane, packed 8B
                int mbase = bm + wm + am * 16 + lg * 4;     // = b*SS + s_base
                int n = bn + wn + nf * 16 + lr;
                int bidx = mbase >> 11, sidx = mbase & (SS - 1);
                s16x4 o;
#pragma unroll
                for (int r = 0; r < 4; ++r)
                    o[r] = (short)f2b((acc[am][nf][r] + bia[nf]) * alpha);
                *(s16x4*)((unsigned short*)Y +
                          (((size_t)(bidx << 10) + n) << 11) + sidx) = o;
            } else {
#pragma unroll
                for (int r = 0; r < 4; ++r) {
                    float o = (acc[am][nf][r] + bia[nf]) * alpha;
                    size_t m = (size_t)(bm + wm + am * 16 + lg * 4 + r);
                    size_t n = (size_t)(bn + wn + nf * 16 + lr);
                    if (OUTMODE == 1) ((unsigned short*)Y)[m * N + n] = f2b(o);
                    else              ((float*)Y)[m * N + n] = o;
                }
            }
        }
}

// ---------------------------------------------------------------------------
// Per-query band bounds via binary search (timestamps sorted per sequence).
// ---------------------------------------------------------------------------
__global__ __launch_bounds__(256)
void band_bounds(const float* __restrict__ ts, int* __restrict__ lo, int* __restrict__ hi)
{
    int idx = blockIdx.x * 256 + threadIdx.x;
    if (idx >= NN) return;
    int b = idx / SS, q = idx % SS;
    const float* t = ts + (size_t)b * SS;
    float tq = t[q];
    float lot = tq - WINDOWF - 1.0f;
    float hit = tq + WINDOWF + 1.0f;
    int l = 0, r = q;
    while (l < r) { int m = (l + r) >> 1; if (t[m] < lot) l = m + 1; else r = m; }
    lo[idx] = l;
    int l2 = q, r2 = SS - 1;
    while (l2 < r2) { int m = (l2 + r2 + 1) >> 1; if (t[m] > hit) r2 = m - 1; else l2 = m; }
    hi[idx] = l2;
}

// ---------------------------------------------------------------------------
// MFMA flash attention, swapped-operand, LDS-free, barrier-free, 2 q-strips
// per wave: K and Vt fragments are strip-independent, so each global load
// feeds TWO MFMAs (halves memory traffic per FLOP, doubles per-tile issue
// density to cover L2 latency). Block = 4 waves x 32 q-rows = 128 q-rows.
// S^T = mfma(K,Q); PV via permuted-k 16x16x32 (both operands permuted).
// ---------------------------------------------------------------------------
__global__ __launch_bounds__(256)
void attn_mfma(const unsigned short* __restrict__ Qb, const unsigned short* __restrict__ Kb,
               const unsigned short* __restrict__ Vt, const float* __restrict__ Tg,
               const int* __restrict__ lo, const int* __restrict__ hi,
               unsigned short* __restrict__ Ab)
{
    const int blk = blockIdx.x;
    const int qt = blk & 15, h = (blk >> 4) & 15, b = blk >> 8;
    const int tid = threadIdx.x;
    const int wid = tid >> 6, l = tid & 63;
    const int lr = l & 15, lg = l >> 4;
    const int qA = qt * 128 + wid * 32;      // strip A rows [qA, qA+16)
    const int qB = qA + 16;                  // strip B rows [qB, qB+16)

    const size_t rowA = (size_t)(b * SS + qA + lr);
    const size_t rowB = (size_t)(b * SS + qB + lr);
    const bf16x8 qfA0 = *(const bf16x8*)(Qb + rowA * DD + h * HDD + lg * 8);
    const bf16x8 qfA1 = *(const bf16x8*)(Qb + rowA * DD + h * HDD + 32 + lg * 8);
    const bf16x8 qfB0 = *(const bf16x8*)(Qb + rowB * DD + h * HDD + lg * 8);
    const bf16x8 qfB1 = *(const bf16x8*)(Qb + rowB * DD + h * HDD + 32 + lg * 8);

    const float* tb = Tg + (size_t)b * SS;
    const float tqA = tb[qA + lr];
    const float tqB = tb[qB + lr];
    const float tq_min = tb[qA];             // uniform (sorted)
    const float tq_max = tb[qB + 15];        // uniform

    const int t0 = lo[b * SS + qA] >> 6;
    const int t1 = hi[b * SS + qB + 15] >> 6;

    const unsigned short* Kbh = Kb + (size_t)b * SS * DD + h * HDD;
    const unsigned short* Vth = Vt + ((size_t)(b * 1024 + h * HDD)) * SS;

    float mA = -1e30f, lA = 0.f, mB = -1e30f, lB = 0.f;
    f32x4 oA[4], oB[4];
#pragma unroll
    for (int df = 0; df < 4; ++df) {
        oA[df] = (f32x4){0.f, 0.f, 0.f, 0.f};
        oB[df] = (f32x4){0.f, 0.f, 0.f, 0.f};
    }

    for (int t = t0; t <= t1; ++t) {
        const int kk0 = t * 64;

        // ---- QK^T for both strips (K frags shared) ----
        f32x4 sA[4], sB[4];
#pragma unroll
        for (int kf = 0; kf < 4; ++kf) {
            const unsigned short* kp = Kbh + (size_t)(kk0 + kf * 16 + lr) * DD;
            bf16x8 ka0 = *(const bf16x8*)(kp + lg * 8);
            bf16x8 ka1 = *(const bf16x8*)(kp + 32 + lg * 8);
            f32x4 zA = (f32x4){0.f, 0.f, 0.f, 0.f};
            zA = __builtin_amdgcn_mfma_f32_16x16x32_bf16(ka0, qfA0, zA, 0, 0, 0);
            zA = __builtin_amdgcn_mfma_f32_16x16x32_bf16(ka1, qfA1, zA, 0, 0, 0);
            sA[kf] = zA;
            f32x4 zB = (f32x4){0.f, 0.f, 0.f, 0.f};
            zB = __builtin_amdgcn_mfma_f32_16x16x32_bf16(ka0, qfB0, zB, 0, 0, 0);
            zB = __builtin_amdgcn_mfma_f32_16x16x32_bf16(ka1, qfB1, zB, 0, 0, 0);
            sB[kf] = zB;
        }

        // ---- exact mask only on boundary tiles (uniform test, 4s margin) ----
        const bool needmask = !((tq_max - tb[kk0] <= WINDOWF - 4.0f) &&
                                (tb[kk0 + 63] - tq_min <= WINDOWF - 4.0f));
        if (needmask) {
#pragma unroll
            for (int kf = 0; kf < 4; ++kf) {
                float4 tk4 = *(const float4*)(tb + kk0 + kf * 16 + lg * 4);
                if (!(fabsf(tqA - tk4.x) <= WINDOWF)) sA[kf][0] = -INFINITY;
                if (!(fabsf(tqA - tk4.y) <= WINDOWF)) sA[kf][1] = -INFINITY;
                if (!(fabsf(tqA - tk4.z) <= WINDOWF)) sA[kf][2] = -INFINITY;
                if (!(fabsf(tqA - tk4.w) <= WINDOWF)) sA[kf][3] = -INFINITY;
                if (!(fabsf(tqB - tk4.x) <= WINDOWF)) sB[kf][0] = -INFINITY;
                if (!(fabsf(tqB - tk4.y) <= WINDOWF)) sB[kf][1] = -INFINITY;
                if (!(fabsf(tqB - tk4.z) <= WINDOWF)) sB[kf][2] = -INFINITY;
                if (!(fabsf(tqB - tk4.w) <= WINDOWF)) sB[kf][3] = -INFINITY;
            }
        }

        // ---- online softmax, strip A ----
        {
            float mt = sA[0][0];
#pragma unroll
            for (int kf = 0; kf < 4; ++kf)
#pragma unroll
                for (int r = 0; r < 4; ++r) mt = fmaxf(mt, sA[kf][r]);
            mt = fmaxf(mt, __shfl_xor(mt, 16));
            mt = fmaxf(mt, __shfl_xor(mt, 32));
            const float mn = fmaxf(mA, mt);
            const float f_ = __builtin_amdgcn_exp2f(mA - mn);
            float rs = 0.f;
#pragma unroll
            for (int kf = 0; kf < 4; ++kf)
#pragma unroll
                for (int r = 0; r < 4; ++r) {
                    float p = __builtin_amdgcn_exp2f(sA[kf][r] - mn);
                    sA[kf][r] = p;
                    rs += p;
                }
            rs += __shfl_xor(rs, 16);
            rs += __shfl_xor(rs, 32);
            lA = lA * f_ + rs;
            mA = mn;
#pragma unroll
            for (int df = 0; df < 4; ++df)
#pragma unroll
                for (int r = 0; r < 4; ++r) oA[df][r] *= f_;
        }
        // ---- online softmax, strip B ----
        {
            float mt = sB[0][0];
#pragma unroll
            for (int kf = 0; kf < 4; ++kf)
#pragma unroll
                for (int r = 0; r < 4; ++r) mt = fmaxf(mt, sB[kf][r]);
            mt = fmaxf(mt, __shfl_xor(mt, 16));
            mt = fmaxf(mt, __shfl_xor(mt, 32));
            const float mn = fmaxf(mB, mt);
            const float f_ = __builtin_amdgcn_exp2f(mB - mn);
            float rs = 0.f;
#pragma unroll
            for (int kf = 0; kf < 4; ++kf)
#pragma unroll
                for (int r = 0; r < 4; ++r) {
                    float p = __builtin_amdgcn_exp2f(sB[kf][r] - mn);
                    sB[kf][r] = p;
                    rs += p;
                }
            rs += __shfl_xor(rs, 16);
            rs += __shfl_xor(rs, 32);
            lB = lB * f_ + rs;
            mB = mn;
#pragma unroll
            for (int df = 0; df < 4; ++df)
#pragma unroll
                for (int r = 0; r < 4; ++r) oB[df][r] *= f_;
        }

        // ---- P^T -> packed bf16 (in-register) ----
        union { unsigned int u[4]; bf16x8 v; } pbA[2], pbB[2];
#pragma unroll
        for (int c = 0; c < 2; ++c) {
            pbA[c].u[0] = cvt_pk_bf16(sA[2 * c][0],     sA[2 * c][1]);
            pbA[c].u[1] = cvt_pk_bf16(sA[2 * c][2],     sA[2 * c][3]);
            pbA[c].u[2] = cvt_pk_bf16(sA[2 * c + 1][0], sA[2 * c + 1][1]);
            pbA[c].u[3] = cvt_pk_bf16(sA[2 * c + 1][2], sA[2 * c + 1][3]);
            pbB[c].u[0] = cvt_pk_bf16(sB[2 * c][0],     sB[2 * c][1]);
            pbB[c].u[1] = cvt_pk_bf16(sB[2 * c][2],     sB[2 * c][3]);
            pbB[c].u[2] = cvt_pk_bf16(sB[2 * c + 1][0], sB[2 * c + 1][1]);
            pbB[c].u[3] = cvt_pk_bf16(sB[2 * c + 1][2], sB[2 * c + 1][3]);
        }

        // ---- O^T += V^T . P^T (va shared between strips) ----
#pragma unroll
        for (int df = 0; df < 4; ++df) {
            const unsigned short* vrow = Vth + (size_t)(df * 16 + lr) * SS + kk0 + lg * 4;
#pragma unroll
            for (int c = 0; c < 2; ++c) {
                union { bf16x4 hh[2]; bf16x8 w; } va;
                va.hh[0] = *(const bf16x4*)(vrow + (2 * c) * 16);
                va.hh[1] = *(const bf16x4*)(vrow + (2 * c + 1) * 16);
                oA[df] = __builtin_amdgcn_mfma_f32_16x16x32_bf16(va.w, pbA[c].v, oA[df], 0, 0, 0);
                oB[df] = __builtin_amdgcn_mfma_f32_16x16x32_bf16(va.w, pbB[c].v, oB[df], 0, 0, 0);
            }
        }
    }

    // finalize both strips: attended[q][d] = O^T / l, packed 8B stores
    const float invA = 1.f / lA, invB = 1.f / lB;
#pragma unroll
    for (int df = 0; df < 4; ++df) {
        s16x4 a, bo_;
#pragma unroll
        for (int r = 0; r < 4; ++r) {
            a[r]   = (short)f2b(oA[df][r] * invA);
            bo_[r] = (short)f2b(oB[df][r] * invB);
        }
        *(s16x4*)(Ab + rowA * DD + h * HDD + df * 16 + lg * 4) = a;
        *(s16x4*)(Ab + rowB * DD + h * HDD + df * 16 + lg * 4) = bo_;
    }
}

// ---------------------------------------------------------------------------
// change_scores[n] = out[n,:] . Wc + bc   (one wave per row)
// ---------------------------------------------------------------------------
__global__ __launch_bounds__(256)
void change_kernel(const float* __restrict__ out, const float* __restrict__ Wc,
                   const float* __restrict__ bc, float* __restrict__ cs)
{
    int row = blockIdx.x * 4 + (threadIdx.x >> 6);
    int lane = threadIdx.x & 63;
    const float* o = out + (size_t)row * DD;
    float sum = 0.f;
#pragma unroll
    for (int k = 0; k < DD / 256; ++k) {
        int c = lane * 4 + k * 256;
        float4 v = *(const float4*)(o + c);
        float4 w = *(const float4*)(Wc + c);
        sum += v.x * w.x + v.y * w.y + v.z * w.z + v.w * w.w;
    }
#pragma unroll
    for (int off = 1; off < 64; off <<= 1) sum += __shfl_xor(sum, off);
    if (lane == 0) cs[row] = sum + bc[0];
}

// ---------------------------------------------------------------------------
extern "C" void kernel_launch(void* const* d_in, const int* in_sizes, int n_in,
                              void* d_out, int out_size, void* d_ws, size_t ws_size,
                              hipStream_t stream)
{
    (void)in_sizes; (void)n_in; (void)out_size; (void)ws_size;
    const float* x  = (const float*)d_in[0];
    const float* ts = (const float*)d_in[1];
    const float* Wq = (const float*)d_in[2];
    const float* bq = (const float*)d_in[3];
    const float* Wk = (const float*)d_in[4];
    const float* bk = (const float*)d_in[5];
    const float* Wv = (const float*)d_in[6];
    const float* bv = (const float*)d_in[7];
    const float* Wo = (const float*)d_in[8];
    const float* bo = (const float*)d_in[9];
    const float* Wc = (const float*)d_in[10];
    const float* bc = (const float*)d_in[11];

    float* out = (float*)d_out;                 // [N*D] output, then [N] change scores

    unsigned short* xb  = (unsigned short*)d_ws;
    unsigned short* Qb  = xb  + (size_t)NN * DD;
    unsigned short* Kb2 = Qb  + (size_t)NN * DD;
    unsigned short* Vtb = Kb2 + (size_t)NN * DD;   // transposed [b][h*64+d][s]
    unsigned short* Abf = Vtb + (size_t)NN * DD;
    unsigned short* Wqb = Abf + (size_t)NN * DD;
    unsigned short* Wkb = Wqb + (size_t)DD * DD;
    unsigned short* Wvb = Wkb + (size_t)DD * DD;
    unsigned short* Wob = Wvb + (size_t)DD * DD;
    int* lo = (int*)(Wob + (size_t)DD * DD);
    int* hi = lo + NN;

    // converts
    cvt_bf16<<<(NN * DD / 4 + 255) / 256, 256, 0, stream>>>(x, xb, NN * DD);
    cvt_bf16<<<(DD * DD / 4 + 255) / 256, 256, 0, stream>>>(Wq, Wqb, DD * DD);
    cvt_bf16<<<(DD * DD / 4 + 255) / 256, 256, 0, stream>>>(Wk, Wkb, DD * DD);
    cvt_bf16<<<(DD * DD / 4 + 255) / 256, 256, 0, stream>>>(Wv, Wvb, DD * DD);
    cvt_bf16<<<(DD * DD / 4 + 255) / 256, 256, 0, stream>>>(Wo, Wob, DD * DD);

    dim3 g(NN / 128, DD / 128);
    gemm_bf16<1><<<g, 256, 0, stream>>>(xb, Wqb, bq, Qb,  NN, DD, DD, SCALE2);
    gemm_bf16<1><<<g, 256, 0, stream>>>(xb, Wkb, bk, Kb2, NN, DD, DD, 1.0f);
    gemm_bf16<2><<<g, 256, 0, stream>>>(xb, Wvb, bv, Vtb, NN, DD, DD, 1.0f);
    band_bounds<<<NN / 256, 256, 0, stream>>>(ts, lo, hi);
    attn_mfma<<<BB * HH * (SS / 128), 256, 0, stream>>>(Qb, Kb2, Vtb, ts, lo, hi, Abf);
    gemm_bf16<0><<<g, 256, 0, stream>>>(Abf, Wob, bo, out, NN, DD, DD, 1.0f);
    change_kernel<<<NN / 4, 256, 0, stream>>>(out, Wc, bc, out + (size_t)NN * DD);
}

// Round 6
// 339.709 us; speedup vs baseline: 1.4749x; 1.1397x over previous
//
#include <hip/hip_runtime.h>
#include <math.h>

#define BB 4
#define SS 2048
#define DD 1024
#define HH 16
#define HDD 64
#define NN (BB*SS)            // 8192 rows
#define WINDOWF 604800.0f     // 7 days
#define LOG2E 1.44269504088896340736f
#define SCALE2 (0.125f * LOG2E)   // 1/sqrt(64) * log2(e): scores in log2 domain

typedef __attribute__((ext_vector_type(8))) short bf16x8;
typedef __attribute__((ext_vector_type(4))) short bf16x4;
typedef __attribute__((ext_vector_type(4))) short s16x4;
typedef __attribute__((ext_vector_type(4))) float f32x4;

__device__ __forceinline__ unsigned short f2b(float f) {
    unsigned int x = __float_as_uint(f);
    unsigned int r = x + 0x7FFFu + ((x >> 16) & 1u);
    return (unsigned short)(r >> 16);
}

__device__ __forceinline__ unsigned int cvt_pk_bf16(float lo, float hi) {
    unsigned int r;
    asm("v_cvt_pk_bf16_f32 %0, %1, %2" : "=v"(r) : "v"(lo), "v"(hi));
    return r;
}

// ---------------------------------------------------------------------------
// f32 -> bf16 (RTN), vectorized
// ---------------------------------------------------------------------------
__global__ __launch_bounds__(256)
void cvt_bf16(const float* __restrict__ src, unsigned short* __restrict__ dst, int n)
{
    int i = (blockIdx.x * 256 + threadIdx.x) * 4;
    if (i >= n) return;
    float4 v = *(const float4*)(src + i);
    s16x4 o;
    o[0] = (short)f2b(v.x); o[1] = (short)f2b(v.y);
    o[2] = (short)f2b(v.z); o[3] = (short)f2b(v.w);
    *(s16x4*)(dst + i) = o;
}

// ---------------------------------------------------------------------------
// bf16 MFMA GEMM: Y = (A @ Bw^T + bias) * alpha
// OUTMODE: 0 = f32 row-major, 1 = bf16 row-major,
//          2 = bf16 transposed Vt layout [b][channel][s] (channel = h*64+d)
// ---------------------------------------------------------------------------
template<int OUTMODE>
__global__ __launch_bounds__(256)
void gemm_bf16(const unsigned short* __restrict__ A,
               const unsigned short* __restrict__ Bw,
               const float* __restrict__ bias,
               void* __restrict__ Y, int M, int N, int K, float alpha)
{
    constexpr int BM = 128, BN = 128, BK = 32;
    constexpr int LDA = 40;                       // padded row, elems
    __shared__ unsigned short As[BM * LDA];
    __shared__ unsigned short Bs[BN * LDA];

    const int bm = blockIdx.x * BM;
    const int bn = blockIdx.y * BN;
    const int tid = threadIdx.x;
    const int wid = tid >> 6, l = tid & 63;
    const int wm = (wid >> 1) * 64, wn = (wid & 1) * 64;
    const int lr = l & 15, lg = l >> 4;

    f32x4 acc[4][4];
#pragma unroll
    for (int i = 0; i < 4; ++i)
#pragma unroll
        for (int j = 0; j < 4; ++j) acc[i][j] = (f32x4){0.f, 0.f, 0.f, 0.f};

    for (int k0 = 0; k0 < K; k0 += BK) {
        bf16x8 av[2], bv[2];
#pragma unroll
        for (int t = 0; t < 2; ++t) {
            int idx = t * 256 + tid;
            int r = idx >> 2, c = (idx & 3) * 8;
            av[t] = *(const bf16x8*)(A  + (size_t)(bm + r) * K + k0 + c);
            bv[t] = *(const bf16x8*)(Bw + (size_t)(bn + r) * K + k0 + c);
        }
        __syncthreads();
#pragma unroll
        for (int t = 0; t < 2; ++t) {
            int idx = t * 256 + tid;
            int r = idx >> 2, c = (idx & 3) * 8;
            *(bf16x8*)&As[r * LDA + c] = av[t];
            *(bf16x8*)&Bs[r * LDA + c] = bv[t];
        }
        __syncthreads();

        bf16x8 af[4], bf[4];
#pragma unroll
        for (int am = 0; am < 4; ++am)
            af[am] = *(const bf16x8*)&As[(wm + am * 16 + lr) * LDA + lg * 8];
#pragma unroll
        for (int nf = 0; nf < 4; ++nf)
            bf[nf] = *(const bf16x8*)&Bs[(wn + nf * 16 + lr) * LDA + lg * 8];
#pragma unroll
        for (int am = 0; am < 4; ++am)
#pragma unroll
            for (int nf = 0; nf < 4; ++nf)
                acc[am][nf] = __builtin_amdgcn_mfma_f32_16x16x32_bf16(
                    af[am], bf[nf], acc[am][nf], 0, 0, 0);
    }

    float bia[4];
#pragma unroll
    for (int nf = 0; nf < 4; ++nf) bia[nf] = bias[bn + wn + nf * 16 + lr];

#pragma unroll
    for (int am = 0; am < 4; ++am)
#pragma unroll
        for (int nf = 0; nf < 4; ++nf) {
            if (OUTMODE == 2) {
                // transposed Vt store: 4 consecutive s per lane, packed 8B
                int mbase = bm + wm + am * 16 + lg * 4;     // = b*SS + s_base
                int n = bn + wn + nf * 16 + lr;
                int bidx = mbase >> 11, sidx = mbase & (SS - 1);
                s16x4 o;
#pragma unroll
                for (int r = 0; r < 4; ++r)
                    o[r] = (short)f2b((acc[am][nf][r] + bia[nf]) * alpha);
                *(s16x4*)((unsigned short*)Y +
                          (((size_t)(bidx << 10) + n) << 11) + sidx) = o;
            } else {
#pragma unroll
                for (int r = 0; r < 4; ++r) {
                    float o = (acc[am][nf][r] + bia[nf]) * alpha;
                    size_t m = (size_t)(bm + wm + am * 16 + lg * 4 + r);
                    size_t n = (size_t)(bn + wn + nf * 16 + lr);
                    if (OUTMODE == 1) ((unsigned short*)Y)[m * N + n] = f2b(o);
                    else              ((float*)Y)[m * N + n] = o;
                }
            }
        }
}

// ---------------------------------------------------------------------------
// Per-query band bounds via binary search (timestamps sorted per sequence).
// ---------------------------------------------------------------------------
__global__ __launch_bounds__(256)
void band_bounds(const float* __restrict__ ts, int* __restrict__ lo, int* __restrict__ hi)
{
    int idx = blockIdx.x * 256 + threadIdx.x;
    if (idx >= NN) return;
    int b = idx / SS, q = idx % SS;
    const float* t = ts + (size_t)b * SS;
    float tq = t[q];
    float lot = tq - WINDOWF - 1.0f;
    float hit = tq + WINDOWF + 1.0f;
    int l = 0, r = q;
    while (l < r) { int m = (l + r) >> 1; if (t[m] < lot) l = m + 1; else r = m; }
    lo[idx] = l;
    int l2 = q, r2 = SS - 1;
    while (l2 < r2) { int m = (l2 + r2 + 1) >> 1; if (t[m] > hit) r2 = m - 1; else l2 = m; }
    hi[idx] = l2;
}

// ---------------------------------------------------------------------------
// MFMA flash attention, swapped-operand, LDS-free, barrier-free, 2 q-strips
// per wave. Round-6 latency fixes:
//  - XCD-aware swizzle: each XCD owns 8 contiguous (b,h) pairs -> K/V slice
//    working set ~1-2 MB fits the 4 MB per-XCD L2 (was ~8 MB, HBM-missing).
//  - K register rotation: QK consumes ka[], then next tile's K loads issue
//    immediately into ka[]; softmax+PV (~400cyc) covers the latency.
//  - V-load hoist: all V fragments issue before softmax, consumed in PV.
// ---------------------------------------------------------------------------
__global__ __launch_bounds__(256)
void attn_mfma(const unsigned short* __restrict__ Qb, const unsigned short* __restrict__ Kb,
               const unsigned short* __restrict__ Vt, const float* __restrict__ Tg,
               const int* __restrict__ lo, const int* __restrict__ hi,
               unsigned short* __restrict__ Ab)
{
    // XCD-aware decode: hw assigns xcd = blockIdx.x % 8 (round-robin).
    const int blk = blockIdx.x;
    const int xcd = blk & 7;
    const int idx = blk >> 3;            // 0..127
    const int bh  = xcd * 8 + (idx >> 4);
    const int qt  = idx & 15;
    const int b = bh >> 4, h = bh & 15;

    const int tid = threadIdx.x;
    const int wid = tid >> 6, l = tid & 63;
    const int lr = l & 15, lg = l >> 4;
    const int qA = qt * 128 + wid * 32;      // strip A rows [qA, qA+16)
    const int qB = qA + 16;                  // strip B rows [qB, qB+16)

    const size_t rowA = (size_t)(b * SS + qA + lr);
    const size_t rowB = (size_t)(b * SS + qB + lr);
    const bf16x8 qfA0 = *(const bf16x8*)(Qb + rowA * DD + h * HDD + lg * 8);
    const bf16x8 qfA1 = *(const bf16x8*)(Qb + rowA * DD + h * HDD + 32 + lg * 8);
    const bf16x8 qfB0 = *(const bf16x8*)(Qb + rowB * DD + h * HDD + lg * 8);
    const bf16x8 qfB1 = *(const bf16x8*)(Qb + rowB * DD + h * HDD + 32 + lg * 8);

    const float* tb = Tg + (size_t)b * SS;
    const float tqA = tb[qA + lr];
    const float tqB = tb[qB + lr];
    const float tq_min = tb[qA];             // uniform (sorted)
    const float tq_max = tb[qB + 15];        // uniform

    const int t0 = lo[b * SS + qA] >> 6;
    const int t1 = hi[b * SS + qB + 15] >> 6;

    const unsigned short* Kbh = Kb + (size_t)b * SS * DD + h * HDD;
    const unsigned short* Vth = Vt + ((size_t)(b * 1024 + h * HDD)) * SS;

    float mA = -1e30f, lA = 0.f, mB = -1e30f, lB = 0.f;
    f32x4 oA[4], oB[4];
#pragma unroll
    for (int df = 0; df < 4; ++df) {
        oA[df] = (f32x4){0.f, 0.f, 0.f, 0.f};
        oB[df] = (f32x4){0.f, 0.f, 0.f, 0.f};
    }

    // preload K(t0) fragments
    bf16x8 ka[8];
#pragma unroll
    for (int kf = 0; kf < 4; ++kf) {
        const unsigned short* kp = Kbh + (size_t)(t0 * 64 + kf * 16 + lr) * DD;
        ka[2 * kf]     = *(const bf16x8*)(kp + lg * 8);
        ka[2 * kf + 1] = *(const bf16x8*)(kp + 32 + lg * 8);
    }

    for (int t = t0; t <= t1; ++t) {
        const int kk0 = t * 64;

        // ---- QK^T for both strips (consumes ka) ----
        f32x4 sA[4], sB[4];
#pragma unroll
        for (int kf = 0; kf < 4; ++kf) {
            f32x4 zA = (f32x4){0.f, 0.f, 0.f, 0.f};
            zA = __builtin_amdgcn_mfma_f32_16x16x32_bf16(ka[2 * kf],     qfA0, zA, 0, 0, 0);
            zA = __builtin_amdgcn_mfma_f32_16x16x32_bf16(ka[2 * kf + 1], qfA1, zA, 0, 0, 0);
            sA[kf] = zA;
            f32x4 zB = (f32x4){0.f, 0.f, 0.f, 0.f};
            zB = __builtin_amdgcn_mfma_f32_16x16x32_bf16(ka[2 * kf],     qfB0, zB, 0, 0, 0);
            zB = __builtin_amdgcn_mfma_f32_16x16x32_bf16(ka[2 * kf + 1], qfB1, zB, 0, 0, 0);
            sB[kf] = zB;
        }

        // ---- prefetch K(t+1) into ka (covered by softmax+PV below) ----
        if (t < t1) {
            const int kn0 = kk0 + 64;
#pragma unroll
            for (int kf = 0; kf < 4; ++kf) {
                const unsigned short* kp = Kbh + (size_t)(kn0 + kf * 16 + lr) * DD;
                ka[2 * kf]     = *(const bf16x8*)(kp + lg * 8);
                ka[2 * kf + 1] = *(const bf16x8*)(kp + 32 + lg * 8);
            }
        }

        // ---- V loads for current tile (hoisted; consumed in PV) ----
        bf16x4 vh[8][2];
#pragma unroll
        for (int df = 0; df < 4; ++df) {
            const unsigned short* vrow = Vth + (size_t)(df * 16 + lr) * SS + kk0 + lg * 4;
#pragma unroll
            for (int c = 0; c < 2; ++c) {
                vh[df * 2 + c][0] = *(const bf16x4*)(vrow + (2 * c) * 16);
                vh[df * 2 + c][1] = *(const bf16x4*)(vrow + (2 * c + 1) * 16);
            }
        }

        // ---- exact mask only on boundary tiles (uniform test, 4s margin) ----
        const bool needmask = !((tq_max - tb[kk0] <= WINDOWF - 4.0f) &&
                                (tb[kk0 + 63] - tq_min <= WINDOWF - 4.0f));
        if (needmask) {
#pragma unroll
            for (int kf = 0; kf < 4; ++kf) {
                float4 tk4 = *(const float4*)(tb + kk0 + kf * 16 + lg * 4);
                if (!(fabsf(tqA - tk4.x) <= WINDOWF)) sA[kf][0] = -INFINITY;
                if (!(fabsf(tqA - tk4.y) <= WINDOWF)) sA[kf][1] = -INFINITY;
                if (!(fabsf(tqA - tk4.z) <= WINDOWF)) sA[kf][2] = -INFINITY;
                if (!(fabsf(tqA - tk4.w) <= WINDOWF)) sA[kf][3] = -INFINITY;
                if (!(fabsf(tqB - tk4.x) <= WINDOWF)) sB[kf][0] = -INFINITY;
                if (!(fabsf(tqB - tk4.y) <= WINDOWF)) sB[kf][1] = -INFINITY;
                if (!(fabsf(tqB - tk4.z) <= WINDOWF)) sB[kf][2] = -INFINITY;
                if (!(fabsf(tqB - tk4.w) <= WINDOWF)) sB[kf][3] = -INFINITY;
            }
        }

        // ---- online softmax, strip A ----
        {
            float mt = sA[0][0];
#pragma unroll
            for (int kf = 0; kf < 4; ++kf)
#pragma unroll
                for (int r = 0; r < 4; ++r) mt = fmaxf(mt, sA[kf][r]);
            mt = fmaxf(mt, __shfl_xor(mt, 16));
            mt = fmaxf(mt, __shfl_xor(mt, 32));
            const float mn = fmaxf(mA, mt);
            const float f_ = __builtin_amdgcn_exp2f(mA - mn);
            float rs = 0.f;
#pragma unroll
            for (int kf = 0; kf < 4; ++kf)
#pragma unroll
                for (int r = 0; r < 4; ++r) {
                    float p = __builtin_amdgcn_exp2f(sA[kf][r] - mn);
                    sA[kf][r] = p;
                    rs += p;
                }
            rs += __shfl_xor(rs, 16);
            rs += __shfl_xor(rs, 32);
            lA = lA * f_ + rs;
            mA = mn;
#pragma unroll
            for (int df = 0; df < 4; ++df)
#pragma unroll
                for (int r = 0; r < 4; ++r) oA[df][r] *= f_;
        }
        // ---- online softmax, strip B ----
        {
            float mt = sB[0][0];
#pragma unroll
            for (int kf = 0; kf < 4; ++kf)
#pragma unroll
                for (int r = 0; r < 4; ++r) mt = fmaxf(mt, sB[kf][r]);
            mt = fmaxf(mt, __shfl_xor(mt, 16));
            mt = fmaxf(mt, __shfl_xor(mt, 32));
            const float mn = fmaxf(mB, mt);
            const float f_ = __builtin_amdgcn_exp2f(mB - mn);
            float rs = 0.f;
#pragma unroll
            for (int kf = 0; kf < 4; ++kf)
#pragma unroll
                for (int r = 0; r < 4; ++r) {
                    float p = __builtin_amdgcn_exp2f(sB[kf][r] - mn);
                    sB[kf][r] = p;
                    rs += p;
                }
            rs += __shfl_xor(rs, 16);
            rs += __shfl_xor(rs, 32);
            lB = lB * f_ + rs;
            mB = mn;
#pragma unroll
            for (int df = 0; df < 4; ++df)
#pragma unroll
                for (int r = 0; r < 4; ++r) oB[df][r] *= f_;
        }

        // ---- P^T -> packed bf16 (in-register) ----
        union { unsigned int u[4]; bf16x8 v; } pbA[2], pbB[2];
#pragma unroll
        for (int c = 0; c < 2; ++c) {
            pbA[c].u[0] = cvt_pk_bf16(sA[2 * c][0],     sA[2 * c][1]);
            pbA[c].u[1] = cvt_pk_bf16(sA[2 * c][2],     sA[2 * c][3]);
            pbA[c].u[2] = cvt_pk_bf16(sA[2 * c + 1][0], sA[2 * c + 1][1]);
            pbA[c].u[3] = cvt_pk_bf16(sA[2 * c + 1][2], sA[2 * c + 1][3]);
            pbB[c].u[0] = cvt_pk_bf16(sB[2 * c][0],     sB[2 * c][1]);
            pbB[c].u[1] = cvt_pk_bf16(sB[2 * c][2],     sB[2 * c][3]);
            pbB[c].u[2] = cvt_pk_bf16(sB[2 * c + 1][0], sB[2 * c + 1][1]);
            pbB[c].u[3] = cvt_pk_bf16(sB[2 * c + 1][2], sB[2 * c + 1][3]);
        }

        // ---- O^T += V^T . P^T (va shared between strips) ----
#pragma unroll
        for (int df = 0; df < 4; ++df) {
#pragma unroll
            for (int c = 0; c < 2; ++c) {
                union { bf16x4 hh[2]; bf16x8 w; } va;
                va.hh[0] = vh[df * 2 + c][0];
                va.hh[1] = vh[df * 2 + c][1];
                oA[df] = __builtin_amdgcn_mfma_f32_16x16x32_bf16(va.w, pbA[c].v, oA[df], 0, 0, 0);
                oB[df] = __builtin_amdgcn_mfma_f32_16x16x32_bf16(va.w, pbB[c].v, oB[df], 0, 0, 0);
            }
        }
    }

    // finalize both strips: attended[q][d] = O^T / l, packed 8B stores
    const float invA = 1.f / lA, invB = 1.f / lB;
#pragma unroll
    for (int df = 0; df < 4; ++df) {
        s16x4 a, bo_;
#pragma unroll
        for (int r = 0; r < 4; ++r) {
            a[r]   = (short)f2b(oA[df][r] * invA);
            bo_[r] = (short)f2b(oB[df][r] * invB);
        }
        *(s16x4*)(Ab + rowA * DD + h * HDD + df * 16 + lg * 4) = a;
        *(s16x4*)(Ab + rowB * DD + h * HDD + df * 16 + lg * 4) = bo_;
    }
}

// ---------------------------------------------------------------------------
// change_scores[n] = out[n,:] . Wc + bc   (one wave per row)
// ---------------------------------------------------------------------------
__global__ __launch_bounds__(256)
void change_kernel(const float* __restrict__ out, const float* __restrict__ Wc,
                   const float* __restrict__ bc, float* __restrict__ cs)
{
    int row = blockIdx.x * 4 + (threadIdx.x >> 6);
    int lane = threadIdx.x & 63;
    const float* o = out + (size_t)row * DD;
    float sum = 0.f;
#pragma unroll
    for (int k = 0; k < DD / 256; ++k) {
        int c = lane * 4 + k * 256;
        float4 v = *(const float4*)(o + c);
        float4 w = *(const float4*)(Wc + c);
        sum += v.x * w.x + v.y * w.y + v.z * w.z + v.w * w.w;
    }
#pragma unroll
    for (int off = 1; off < 64; off <<= 1) sum += __shfl_xor(sum, off);
    if (lane == 0) cs[row] = sum + bc[0];
}

// ---------------------------------------------------------------------------
extern "C" void kernel_launch(void* const* d_in, const int* in_sizes, int n_in,
                              void* d_out, int out_size, void* d_ws, size_t ws_size,
                              hipStream_t stream)
{
    (void)in_sizes; (void)n_in; (void)out_size; (void)ws_size;
    const float* x  = (const float*)d_in[0];
    const float* ts = (const float*)d_in[1];
    const float* Wq = (const float*)d_in[2];
    const float* bq = (const float*)d_in[3];
    const float* Wk = (const float*)d_in[4];
    const float* bk = (const float*)d_in[5];
    const float* Wv = (const float*)d_in[6];
    const float* bv = (const float*)d_in[7];
    const float* Wo = (const float*)d_in[8];
    const float* bo = (const float*)d_in[9];
    const float* Wc = (const float*)d_in[10];
    const float* bc = (const float*)d_in[11];

    float* out = (float*)d_out;                 // [N*D] output, then [N] change scores

    unsigned short* xb  = (unsigned short*)d_ws;
    unsigned short* Qb  = xb  + (size_t)NN * DD;
    unsigned short* Kb2 = Qb  + (size_t)NN * DD;
    unsigned short* Vtb = Kb2 + (size_t)NN * DD;   // transposed [b][h*64+d][s]
    unsigned short* Abf = Vtb + (size_t)NN * DD;
    unsigned short* Wqb = Abf + (size_t)NN * DD;
    unsigned short* Wkb = Wqb + (size_t)DD * DD;
    unsigned short* Wvb = Wkb + (size_t)DD * DD;
    unsigned short* Wob = Wvb + (size_t)DD * DD;
    int* lo = (int*)(Wob + (size_t)DD * DD);
    int* hi = lo + NN;

    // converts
    cvt_bf16<<<(NN * DD / 4 + 255) / 256, 256, 0, stream>>>(x, xb, NN * DD);
    cvt_bf16<<<(DD * DD / 4 + 255) / 256, 256, 0, stream>>>(Wq, Wqb, DD * DD);
    cvt_bf16<<<(DD * DD / 4 + 255) / 256, 256, 0, stream>>>(Wk, Wkb, DD * DD);
    cvt_bf16<<<(DD * DD / 4 + 255) / 256, 256, 0, stream>>>(Wv, Wvb, DD * DD);
    cvt_bf16<<<(DD * DD / 4 + 255) / 256, 256, 0, stream>>>(Wo, Wob, DD * DD);

    dim3 g(NN / 128, DD / 128);
    gemm_bf16<1><<<g, 256, 0, stream>>>(xb, Wqb, bq, Qb,  NN, DD, DD, SCALE2);
    gemm_bf16<1><<<g, 256, 0, stream>>>(xb, Wkb, bk, Kb2, NN, DD, DD, 1.0f);
    gemm_bf16<2><<<g, 256, 0, stream>>>(xb, Wvb, bv, Vtb, NN, DD, DD, 1.0f);
    band_bounds<<<NN / 256, 256, 0, stream>>>(ts, lo, hi);
    attn_mfma<<<BB * HH * (SS / 128), 256, 0, stream>>>(Qb, Kb2, Vtb, ts, lo, hi, Abf);
    gemm_bf16<0><<<g, 256, 0, stream>>>(Abf, Wob, bo, out, NN, DD, DD, 1.0f);
    change_kernel<<<NN / 4, 256, 0, stream>>>(out, Wc, bc, out + (size_t)NN * DD);
}

// Round 7
// 234.486 us; speedup vs baseline: 2.1367x; 1.4487x over previous
//
#include <hip/hip_runtime.h>
#include <math.h>

#define BB 4
#define SS 2048
#define DD 1024
#define HH 16
#define HDD 64
#define NN (BB*SS)            // 8192 rows
#define WINDOWF 604800.0f     // 7 days
#define LOG2E 1.44269504088896340736f
#define SCALE2 (0.125f * LOG2E)   // 1/sqrt(64) * log2(e): scores in log2 domain

typedef __attribute__((ext_vector_type(8))) short bf16x8;
typedef __attribute__((ext_vector_type(4))) short bf16x4;
typedef __attribute__((ext_vector_type(4))) short s16x4;
typedef __attribute__((ext_vector_type(4))) float f32x4;

__device__ __forceinline__ unsigned short f2b(float f) {
    unsigned int x = __float_as_uint(f);
    unsigned int r = x + 0x7FFFu + ((x >> 16) & 1u);
    return (unsigned short)(r >> 16);
}

__device__ __forceinline__ unsigned int cvt_pk_bf16(float lo, float hi) {
    unsigned int r;
    asm("v_cvt_pk_bf16_f32 %0, %1, %2" : "=v"(r) : "v"(lo), "v"(hi));
    return r;
}

// ---------------------------------------------------------------------------
// f32 -> bf16 (RTN), vectorized
// ---------------------------------------------------------------------------
__global__ __launch_bounds__(256)
void cvt_bf16(const float* __restrict__ src, unsigned short* __restrict__ dst, int n)
{
    int i = (blockIdx.x * 256 + threadIdx.x) * 4;
    if (i >= n) return;
    float4 v = *(const float4*)(src + i);
    s16x4 o;
    o[0] = (short)f2b(v.x); o[1] = (short)f2b(v.y);
    o[2] = (short)f2b(v.z); o[3] = (short)f2b(v.w);
    *(s16x4*)(dst + i) = o;
}

// ---------------------------------------------------------------------------
// bf16 MFMA GEMM: Y = (A @ Bw^T + bias) * alpha
// OUTMODE: 0 = f32 row-major, 1 = bf16 row-major,
//          2 = bf16 transposed Vt layout [b][channel][s] (channel = h*64+d)
// ---------------------------------------------------------------------------
template<int OUTMODE>
__global__ __launch_bounds__(256)
void gemm_bf16(const unsigned short* __restrict__ A,
               const unsigned short* __restrict__ Bw,
               const float* __restrict__ bias,
               void* __restrict__ Y, int M, int N, int K, float alpha)
{
    constexpr int BM = 128, BN = 128, BK = 32;
    constexpr int LDA = 40;                       // padded row, elems
    __shared__ unsigned short As[BM * LDA];
    __shared__ unsigned short Bs[BN * LDA];

    const int bm = blockIdx.x * BM;
    const int bn = blockIdx.y * BN;
    const int tid = threadIdx.x;
    const int wid = tid >> 6, l = tid & 63;
    const int wm = (wid >> 1) * 64, wn = (wid & 1) * 64;
    const int lr = l & 15, lg = l >> 4;

    f32x4 acc[4][4];
#pragma unroll
    for (int i = 0; i < 4; ++i)
#pragma unroll
        for (int j = 0; j < 4; ++j) acc[i][j] = (f32x4){0.f, 0.f, 0.f, 0.f};

    for (int k0 = 0; k0 < K; k0 += BK) {
        bf16x8 av[2], bv[2];
#pragma unroll
        for (int t = 0; t < 2; ++t) {
            int idx = t * 256 + tid;
            int r = idx >> 2, c = (idx & 3) * 8;
            av[t] = *(const bf16x8*)(A  + (size_t)(bm + r) * K + k0 + c);
            bv[t] = *(const bf16x8*)(Bw + (size_t)(bn + r) * K + k0 + c);
        }
        __syncthreads();
#pragma unroll
        for (int t = 0; t < 2; ++t) {
            int idx = t * 256 + tid;
            int r = idx >> 2, c = (idx & 3) * 8;
            *(bf16x8*)&As[r * LDA + c] = av[t];
            *(bf16x8*)&Bs[r * LDA + c] = bv[t];
        }
        __syncthreads();

        bf16x8 af[4], bf[4];
#pragma unroll
        for (int am = 0; am < 4; ++am)
            af[am] = *(const bf16x8*)&As[(wm + am * 16 + lr) * LDA + lg * 8];
#pragma unroll
        for (int nf = 0; nf < 4; ++nf)
            bf[nf] = *(const bf16x8*)&Bs[(wn + nf * 16 + lr) * LDA + lg * 8];
#pragma unroll
        for (int am = 0; am < 4; ++am)
#pragma unroll
            for (int nf = 0; nf < 4; ++nf)
                acc[am][nf] = __builtin_amdgcn_mfma_f32_16x16x32_bf16(
                    af[am], bf[nf], acc[am][nf], 0, 0, 0);
    }

    float bia[4];
#pragma unroll
    for (int nf = 0; nf < 4; ++nf) bia[nf] = bias[bn + wn + nf * 16 + lr];

#pragma unroll
    for (int am = 0; am < 4; ++am)
#pragma unroll
        for (int nf = 0; nf < 4; ++nf) {
            if (OUTMODE == 2) {
                // transposed Vt store: 4 consecutive s per lane, packed 8B
                int mbase = bm + wm + am * 16 + lg * 4;     // = b*SS + s_base
                int n = bn + wn + nf * 16 + lr;
                int bidx = mbase >> 11, sidx = mbase & (SS - 1);
                s16x4 o;
#pragma unroll
                for (int r = 0; r < 4; ++r)
                    o[r] = (short)f2b((acc[am][nf][r] + bia[nf]) * alpha);
                *(s16x4*)((unsigned short*)Y +
                          (((size_t)(bidx << 10) + n) << 11) + sidx) = o;
            } else {
#pragma unroll
                for (int r = 0; r < 4; ++r) {
                    float o = (acc[am][nf][r] + bia[nf]) * alpha;
                    size_t m = (size_t)(bm + wm + am * 16 + lg * 4 + r);
                    size_t n = (size_t)(bn + wn + nf * 16 + lr);
                    if (OUTMODE == 1) ((unsigned short*)Y)[m * N + n] = f2b(o);
                    else              ((float*)Y)[m * N + n] = o;
                }
            }
        }
}

// ---------------------------------------------------------------------------
// Per-query band bounds via binary search (timestamps sorted per sequence).
// ---------------------------------------------------------------------------
__global__ __launch_bounds__(256)
void band_bounds(const float* __restrict__ ts, int* __restrict__ lo, int* __restrict__ hi)
{
    int idx = blockIdx.x * 256 + threadIdx.x;
    if (idx >= NN) return;
    int b = idx / SS, q = idx % SS;
    const float* t = ts + (size_t)b * SS;
    float tq = t[q];
    float lot = tq - WINDOWF - 1.0f;
    float hit = tq + WINDOWF + 1.0f;
    int l = 0, r = q;
    while (l < r) { int m = (l + r) >> 1; if (t[m] < lot) l = m + 1; else r = m; }
    lo[idx] = l;
    int l2 = q, r2 = SS - 1;
    while (l2 < r2) { int m = (l2 + r2 + 1) >> 1; if (t[m] > hit) r2 = m - 1; else l2 = m; }
    hi[idx] = l2;
}

// ---------------------------------------------------------------------------
// MFMA flash attention. Round-7: cooperative LDS staging of K/V tiles
// (shared across the 4 waves -> 4x less L1/L2 traffic), 2-phase pipeline:
//   write staged regs -> barrier -> issue t+1 global loads -> compute tile t
//   from LDS -> barrier.  XOR swizzle (16B chunk ^= row&7) on BOTH write and
//   read sides gives uniform bank coverage.  Swapped QK^T (S^T lane-local
//   softmax), in-register P via v_cvt_pk_bf16_f32, permuted-k PV.
// ---------------------------------------------------------------------------
__global__ __launch_bounds__(256)
void attn_mfma(const unsigned short* __restrict__ Qb, const unsigned short* __restrict__ Kb,
               const unsigned short* __restrict__ Vt, const float* __restrict__ Tg,
               const int* __restrict__ lo, const int* __restrict__ hi,
               unsigned short* __restrict__ Ab)
{
    __shared__ unsigned short Ks[64 * 64];   // [key r][dim], 16B-chunk swizzled
    __shared__ unsigned short Vs[64 * 64];   // [dim d][key], 16B-chunk swizzled

    // XCD-aware decode: hw assigns xcd = blockIdx.x % 8 (round-robin).
    const int blk = blockIdx.x;
    const int xcd = blk & 7;
    const int idx = blk >> 3;            // 0..127
    const int bh  = xcd * 8 + (idx >> 4);
    const int qt  = idx & 15;
    const int b = bh >> 4, h = bh & 15;

    const int tid = threadIdx.x;
    const int wid = tid >> 6, l = tid & 63;
    const int lr = l & 15, lg = l >> 4;
    const int qA = qt * 128 + wid * 32;      // strip A rows [qA, qA+16)
    const int qB = qA + 16;                  // strip B rows [qB, qB+16)

    const size_t rowA = (size_t)(b * SS + qA + lr);
    const size_t rowB = (size_t)(b * SS + qB + lr);
    const bf16x8 qfA0 = *(const bf16x8*)(Qb + rowA * DD + h * HDD + lg * 8);
    const bf16x8 qfA1 = *(const bf16x8*)(Qb + rowA * DD + h * HDD + 32 + lg * 8);
    const bf16x8 qfB0 = *(const bf16x8*)(Qb + rowB * DD + h * HDD + lg * 8);
    const bf16x8 qfB1 = *(const bf16x8*)(Qb + rowB * DD + h * HDD + 32 + lg * 8);

    const float* tb = Tg + (size_t)b * SS;
    const float tqA = tb[qA + lr];
    const float tqB = tb[qB + lr];
    const float tq_min = tb[qA];             // uniform per wave (sorted)
    const float tq_max = tb[qB + 15];

    // block-uniform band (staging is cooperative)
    const int t0 = lo[b * SS + qt * 128] >> 6;
    const int t1 = hi[b * SS + qt * 128 + 127] >> 6;

    const unsigned short* Kbh = Kb + (size_t)b * SS * DD + h * HDD;
    const unsigned short* Vth = Vt + ((size_t)(b * 1024 + h * HDD)) * SS;

    // staging map: 8 threads/row, 16B each; two passes of 32 rows
    const int sr = tid >> 3;                 // 0..31
    const int sc = tid & 7;                  // 16B chunk index

    float mA = -1e30f, lA = 0.f, mB = -1e30f, lB = 0.f;
    f32x4 oA[4], oB[4];
#pragma unroll
    for (int df = 0; df < 4; ++df) {
        oA[df] = (f32x4){0.f, 0.f, 0.f, 0.f};
        oB[df] = (f32x4){0.f, 0.f, 0.f, 0.f};
    }

    // prologue: issue tile-t0 staging loads into regs
    bf16x8 kst[2], vst[2];
#pragma unroll
    for (int p = 0; p < 2; ++p) {
        int r = p * 32 + sr;
        kst[p] = *(const bf16x8*)(Kbh + (size_t)(t0 * 64 + r) * DD + sc * 8);
        vst[p] = *(const bf16x8*)(Vth + (size_t)r * SS + t0 * 64 + sc * 8);
    }

    for (int t = t0; t <= t1; ++t) {
        const int kk0 = t * 64;

        // ---- write staged regs -> LDS (16B-chunk XOR swizzle) ----
#pragma unroll
        for (int p = 0; p < 2; ++p) {
            int r = p * 32 + sr;
            int off = r * 64 + (((sc ^ (r & 7)) * 8));
            *(bf16x8*)&Ks[off] = kst[p];
            *(bf16x8*)&Vs[off] = vst[p];
        }
        __syncthreads();

        // ---- issue next tile's staging loads (covered by compute below) ----
        if (t < t1) {
            const int kn0 = kk0 + 64;
#pragma unroll
            for (int p = 0; p < 2; ++p) {
                int r = p * 32 + sr;
                kst[p] = *(const bf16x8*)(Kbh + (size_t)(kn0 + r) * DD + sc * 8);
                vst[p] = *(const bf16x8*)(Vth + (size_t)r * SS + kn0 + sc * 8);
            }
        }

        // ---- QK^T for both strips from LDS ----
        f32x4 sA[4], sB[4];
        __builtin_amdgcn_s_setprio(1);
#pragma unroll
        for (int kf = 0; kf < 4; ++kf) {
            const int r = kf * 16 + lr;
            const int x = (r & 7);
            bf16x8 ka0 = *(const bf16x8*)&Ks[r * 64 + ((lg ^ x) * 8)];
            bf16x8 ka1 = *(const bf16x8*)&Ks[r * 64 + (((4 + lg) ^ x) * 8)];
            f32x4 zA = (f32x4){0.f, 0.f, 0.f, 0.f};
            zA = __builtin_amdgcn_mfma_f32_16x16x32_bf16(ka0, qfA0, zA, 0, 0, 0);
            zA = __builtin_amdgcn_mfma_f32_16x16x32_bf16(ka1, qfA1, zA, 0, 0, 0);
            sA[kf] = zA;
            f32x4 zB = (f32x4){0.f, 0.f, 0.f, 0.f};
            zB = __builtin_amdgcn_mfma_f32_16x16x32_bf16(ka0, qfB0, zB, 0, 0, 0);
            zB = __builtin_amdgcn_mfma_f32_16x16x32_bf16(ka1, qfB1, zB, 0, 0, 0);
            sB[kf] = zB;
        }
        __builtin_amdgcn_s_setprio(0);

        // ---- exact mask only on boundary tiles (uniform test, 4s margin) ----
        const bool needmask = !((tq_max - tb[kk0] <= WINDOWF - 4.0f) &&
                                (tb[kk0 + 63] - tq_min <= WINDOWF - 4.0f));
        if (needmask) {
#pragma unroll
            for (int kf = 0; kf < 4; ++kf) {
                float4 tk4 = *(const float4*)(tb + kk0 + kf * 16 + lg * 4);
                if (!(fabsf(tqA - tk4.x) <= WINDOWF)) sA[kf][0] = -INFINITY;
                if (!(fabsf(tqA - tk4.y) <= WINDOWF)) sA[kf][1] = -INFINITY;
                if (!(fabsf(tqA - tk4.z) <= WINDOWF)) sA[kf][2] = -INFINITY;
                if (!(fabsf(tqA - tk4.w) <= WINDOWF)) sA[kf][3] = -INFINITY;
                if (!(fabsf(tqB - tk4.x) <= WINDOWF)) sB[kf][0] = -INFINITY;
                if (!(fabsf(tqB - tk4.y) <= WINDOWF)) sB[kf][1] = -INFINITY;
                if (!(fabsf(tqB - tk4.z) <= WINDOWF)) sB[kf][2] = -INFINITY;
                if (!(fabsf(tqB - tk4.w) <= WINDOWF)) sB[kf][3] = -INFINITY;
            }
        }

        // ---- online softmax, strip A ----
        {
            float mt = sA[0][0];
#pragma unroll
            for (int kf = 0; kf < 4; ++kf)
#pragma unroll
                for (int r = 0; r < 4; ++r) mt = fmaxf(mt, sA[kf][r]);
            mt = fmaxf(mt, __shfl_xor(mt, 16));
            mt = fmaxf(mt, __shfl_xor(mt, 32));
            const float mn = fmaxf(mA, mt);
            const float f_ = __builtin_amdgcn_exp2f(mA - mn);
            float rs = 0.f;
#pragma unroll
            for (int kf = 0; kf < 4; ++kf)
#pragma unroll
                for (int r = 0; r < 4; ++r) {
                    float p = __builtin_amdgcn_exp2f(sA[kf][r] - mn);
                    sA[kf][r] = p;
                    rs += p;
                }
            rs += __shfl_xor(rs, 16);
            rs += __shfl_xor(rs, 32);
            lA = lA * f_ + rs;
            mA = mn;
#pragma unroll
            for (int df = 0; df < 4; ++df)
#pragma unroll
                for (int r = 0; r < 4; ++r) oA[df][r] *= f_;
        }
        // ---- online softmax, strip B ----
        {
            float mt = sB[0][0];
#pragma unroll
            for (int kf = 0; kf < 4; ++kf)
#pragma unroll
                for (int r = 0; r < 4; ++r) mt = fmaxf(mt, sB[kf][r]);
            mt = fmaxf(mt, __shfl_xor(mt, 16));
            mt = fmaxf(mt, __shfl_xor(mt, 32));
            const float mn = fmaxf(mB, mt);
            const float f_ = __builtin_amdgcn_exp2f(mB - mn);
            float rs = 0.f;
#pragma unroll
            for (int kf = 0; kf < 4; ++kf)
#pragma unroll
                for (int r = 0; r < 4; ++r) {
                    float p = __builtin_amdgcn_exp2f(sB[kf][r] - mn);
                    sB[kf][r] = p;
                    rs += p;
                }
            rs += __shfl_xor(rs, 16);
            rs += __shfl_xor(rs, 32);
            lB = lB * f_ + rs;
            mB = mn;
#pragma unroll
            for (int df = 0; df < 4; ++df)
#pragma unroll
                for (int r = 0; r < 4; ++r) oB[df][r] *= f_;
        }

        // ---- P^T -> packed bf16 (in-register) ----
        union { unsigned int u[4]; bf16x8 v; } pbA[2], pbB[2];
#pragma unroll
        for (int c = 0; c < 2; ++c) {
            pbA[c].u[0] = cvt_pk_bf16(sA[2 * c][0],     sA[2 * c][1]);
            pbA[c].u[1] = cvt_pk_bf16(sA[2 * c][2],     sA[2 * c][3]);
            pbA[c].u[2] = cvt_pk_bf16(sA[2 * c + 1][0], sA[2 * c + 1][1]);
            pbA[c].u[3] = cvt_pk_bf16(sA[2 * c + 1][2], sA[2 * c + 1][3]);
            pbB[c].u[0] = cvt_pk_bf16(sB[2 * c][0],     sB[2 * c][1]);
            pbB[c].u[1] = cvt_pk_bf16(sB[2 * c][2],     sB[2 * c][3]);
            pbB[c].u[2] = cvt_pk_bf16(sB[2 * c + 1][0], sB[2 * c + 1][1]);
            pbB[c].u[3] = cvt_pk_bf16(sB[2 * c + 1][2], sB[2 * c + 1][3]);
        }

        // ---- O^T += V^T . P^T from LDS (va shared between strips) ----
        __builtin_amdgcn_s_setprio(1);
#pragma unroll
        for (int df = 0; df < 4; ++df) {
            const int d = df * 16 + lr;
            const int base = d * 64;
            const int x8 = (d & 7) << 3;     // elem-granularity XOR operand
#pragma unroll
            for (int c = 0; c < 2; ++c) {
                union { bf16x4 hh[2]; bf16x8 w; } va;
                va.hh[0] = *(const bf16x4*)&Vs[base + ((((2 * c) * 16 + lg * 4)) ^ x8)];
                va.hh[1] = *(const bf16x4*)&Vs[base + ((((2 * c + 1) * 16 + lg * 4)) ^ x8)];
                oA[df] = __builtin_amdgcn_mfma_f32_16x16x32_bf16(va.w, pbA[c].v, oA[df], 0, 0, 0);
                oB[df] = __builtin_amdgcn_mfma_f32_16x16x32_bf16(va.w, pbB[c].v, oB[df], 0, 0, 0);
            }
        }
        __builtin_amdgcn_s_setprio(0);

        __syncthreads();   // all waves done reading Ks/Vs before next overwrite
    }

    // finalize both strips: attended[q][d] = O^T / l, packed 8B stores
    const float invA = 1.f / lA, invB = 1.f / lB;
#pragma unroll
    for (int df = 0; df < 4; ++df) {
        s16x4 a, bo_;
#pragma unroll
        for (int r = 0; r < 4; ++r) {
            a[r]   = (short)f2b(oA[df][r] * invA);
            bo_[r] = (short)f2b(oB[df][r] * invB);
        }
        *(s16x4*)(Ab + rowA * DD + h * HDD + df * 16 + lg * 4) = a;
        *(s16x4*)(Ab + rowB * DD + h * HDD + df * 16 + lg * 4) = bo_;
    }
}

// ---------------------------------------------------------------------------
// change_scores[n] = out[n,:] . Wc + bc   (one wave per row)
// ---------------------------------------------------------------------------
__global__ __launch_bounds__(256)
void change_kernel(const float* __restrict__ out, const float* __restrict__ Wc,
                   const float* __restrict__ bc, float* __restrict__ cs)
{
    int row = blockIdx.x * 4 + (threadIdx.x >> 6);
    int lane = threadIdx.x & 63;
    const float* o = out + (size_t)row * DD;
    float sum = 0.f;
#pragma unroll
    for (int k = 0; k < DD / 256; ++k) {
        int c = lane * 4 + k * 256;
        float4 v = *(const float4*)(o + c);
        float4 w = *(const float4*)(Wc + c);
        sum += v.x * w.x + v.y * w.y + v.z * w.z + v.w * w.w;
    }
#pragma unroll
    for (int off = 1; off < 64; off <<= 1) sum += __shfl_xor(sum, off);
    if (lane == 0) cs[row] = sum + bc[0];
}

// ---------------------------------------------------------------------------
extern "C" void kernel_launch(void* const* d_in, const int* in_sizes, int n_in,
                              void* d_out, int out_size, void* d_ws, size_t ws_size,
                              hipStream_t stream)
{
    (void)in_sizes; (void)n_in; (void)out_size; (void)ws_size;
    const float* x  = (const float*)d_in[0];
    const float* ts = (const float*)d_in[1];
    const float* Wq = (const float*)d_in[2];
    const float* bq = (const float*)d_in[3];
    const float* Wk = (const float*)d_in[4];
    const float* bk = (const float*)d_in[5];
    const float* Wv = (const float*)d_in[6];
    const float* bv = (const float*)d_in[7];
    const float* Wo = (const float*)d_in[8];
    const float* bo = (const float*)d_in[9];
    const float* Wc = (const float*)d_in[10];
    const float* bc = (const float*)d_in[11];

    float* out = (float*)d_out;                 // [N*D] output, then [N] change scores

    unsigned short* xb  = (unsigned short*)d_ws;
    unsigned short* Qb  = xb  + (size_t)NN * DD;
    unsigned short* Kb2 = Qb  + (size_t)NN * DD;
    unsigned short* Vtb = Kb2 + (size_t)NN * DD;   // transposed [b][h*64+d][s]
    unsigned short* Abf = Vtb + (size_t)NN * DD;
    unsigned short* Wqb = Abf + (size_t)NN * DD;
    unsigned short* Wkb = Wqb + (size_t)DD * DD;
    unsigned short* Wvb = Wkb + (size_t)DD * DD;
    unsigned short* Wob = Wvb + (size_t)DD * DD;
    int* lo = (int*)(Wob + (size_t)DD * DD);
    int* hi = lo + NN;

    // converts
    cvt_bf16<<<(NN * DD / 4 + 255) / 256, 256, 0, stream>>>(x, xb, NN * DD);
    cvt_bf16<<<(DD * DD / 4 + 255) / 256, 256, 0, stream>>>(Wq, Wqb, DD * DD);
    cvt_bf16<<<(DD * DD / 4 + 255) / 256, 256, 0, stream>>>(Wk, Wkb, DD * DD);
    cvt_bf16<<<(DD * DD / 4 + 255) / 256, 256, 0, stream>>>(Wv, Wvb, DD * DD);
    cvt_bf16<<<(DD * DD / 4 + 255) / 256, 256, 0, stream>>>(Wo, Wob, DD * DD);

    dim3 g(NN / 128, DD / 128);
    gemm_bf16<1><<<g, 256, 0, stream>>>(xb, Wqb, bq, Qb,  NN, DD, DD, SCALE2);
    gemm_bf16<1><<<g, 256, 0, stream>>>(xb, Wkb, bk, Kb2, NN, DD, DD, 1.0f);
    gemm_bf16<2><<<g, 256, 0, stream>>>(xb, Wvb, bv, Vtb, NN, DD, DD, 1.0f);
    band_bounds<<<NN / 256, 256, 0, stream>>>(ts, lo, hi);
    attn_mfma<<<BB * HH * (SS / 128), 256, 0, stream>>>(Qb, Kb2, Vtb, ts, lo, hi, Abf);
    gemm_bf16<0><<<g, 256, 0, stream>>>(Abf, Wob, bo, out, NN, DD, DD, 1.0f);
    change_kernel<<<NN / 4, 256, 0, stream>>>(out, Wc, bc, out + (size_t)NN * DD);
}

// Round 8
// 204.364 us; speedup vs baseline: 2.4517x; 1.1474x over previous
//
#include <hip/hip_runtime.h>
#include <math.h>

#define BB 4
#define SS 2048
#define DD 1024
#define HH 16
#define HDD 64
#define NN (BB*SS)            // 8192 rows
#define WINDOWF 604800.0f     // 7 days
#define LOG2E 1.44269504088896340736f
#define SCALE2 (0.125f * LOG2E)   // 1/sqrt(64) * log2(e): scores in log2 domain

typedef __attribute__((ext_vector_type(8))) short bf16x8;
typedef __attribute__((ext_vector_type(4))) short bf16x4;
typedef __attribute__((ext_vector_type(4))) short s16x4;
typedef __attribute__((ext_vector_type(4))) float f32x4;

__device__ __forceinline__ unsigned short f2b(float f) {
    unsigned int x = __float_as_uint(f);
    unsigned int r = x + 0x7FFFu + ((x >> 16) & 1u);
    return (unsigned short)(r >> 16);
}

__device__ __forceinline__ unsigned int cvt_pk_bf16(float lo, float hi) {
    unsigned int r;
    asm("v_cvt_pk_bf16_f32 %0, %1, %2" : "=v"(r) : "v"(lo), "v"(hi));
    return r;
}

// async global->LDS, 16B per lane; LDS dest = wave-uniform base + lane*16
__device__ __forceinline__ void gload16(const unsigned short* g, unsigned short* l) {
    __builtin_amdgcn_global_load_lds(
        (const __attribute__((address_space(1))) unsigned int*)g,
        (__attribute__((address_space(3))) unsigned int*)l, 16, 0, 0);
}

// ---------------------------------------------------------------------------
// f32 -> bf16 (RTN), vectorized
// ---------------------------------------------------------------------------
__global__ __launch_bounds__(256)
void cvt_bf16(const float* __restrict__ src, unsigned short* __restrict__ dst, int n)
{
    int i = (blockIdx.x * 256 + threadIdx.x) * 4;
    if (i >= n) return;
    float4 v = *(const float4*)(src + i);
    s16x4 o;
    o[0] = (short)f2b(v.x); o[1] = (short)f2b(v.y);
    o[2] = (short)f2b(v.z); o[3] = (short)f2b(v.w);
    *(s16x4*)(dst + i) = o;
}

// ---------------------------------------------------------------------------
// bf16 MFMA GEMM, m97 structure: BK=64, global_load_lds w=16 staging with
// pre-swizzled SOURCE (chunk ^= row&7) + swizzled ds_read (conflict-free),
// 2-barrier K-loop.  Y = (A @ Bw^T + bias) * alpha.
// OUTMODE: 0 = f32 row-major, 1 = bf16 row-major,
//          2 = bf16 transposed Vt layout [b][channel][s] (channel = h*64+d)
// ---------------------------------------------------------------------------
template<int OUTMODE>
__global__ __launch_bounds__(256)
void gemm_bf16(const unsigned short* __restrict__ A,
               const unsigned short* __restrict__ Bw,
               const float* __restrict__ bias,
               void* __restrict__ Y, int M, int N, int K, float alpha)
{
    constexpr int BM = 128, BN = 128, BK = 64;
    __shared__ unsigned short As[BM * BK];    // [row][64 elems], chunk-swizzled
    __shared__ unsigned short Bs[BN * BK];

    const int bm = blockIdx.x * BM;
    const int bn = blockIdx.y * BN;
    const int tid = threadIdx.x;
    const int wid = tid >> 6, l = tid & 63;
    const int wm = (wid >> 1) * 64, wn = (wid & 1) * 64;
    const int lr = l & 15, lg = l >> 4;

    // staging lane map: 8 lanes/row-chunk; src chunk pre-swizzled
    const int srow = l >> 3;                       // 0..7 within 8-row group
    const int schunk = ((l & 7) ^ srow) * 8;       // elem offset in row

    f32x4 acc[4][4];
#pragma unroll
    for (int i = 0; i < 4; ++i)
#pragma unroll
        for (int j = 0; j < 4; ++j) acc[i][j] = (f32x4){0.f, 0.f, 0.f, 0.f};

    for (int k0 = 0; k0 < K; k0 += BK) {
        // stage A,B tiles: wave wid covers rows [wid*32, wid*32+32), 4 instrs each
#pragma unroll
        for (int i = 0; i < 4; ++i) {
            const int r0 = wid * 32 + i * 8;
            gload16(A  + (size_t)(bm + r0 + srow) * K + k0 + schunk, &As[r0 * BK]);
            gload16(Bw + (size_t)(bn + r0 + srow) * K + k0 + schunk, &Bs[r0 * BK]);
        }
        __syncthreads();                           // vmcnt drained -> LDS ready

#pragma unroll
        for (int ks = 0; ks < 2; ++ks) {
            bf16x8 af[4], bf[4];
#pragma unroll
            for (int am = 0; am < 4; ++am) {
                const int row = wm + am * 16 + lr;
                af[am] = *(const bf16x8*)&As[row * BK + (((ks * 4 + lg) ^ (row & 7)) * 8)];
            }
#pragma unroll
            for (int nf = 0; nf < 4; ++nf) {
                const int row = wn + nf * 16 + lr;
                bf[nf] = *(const bf16x8*)&Bs[row * BK + (((ks * 4 + lg) ^ (row & 7)) * 8)];
            }
#pragma unroll
            for (int am = 0; am < 4; ++am)
#pragma unroll
                for (int nf = 0; nf < 4; ++nf)
                    acc[am][nf] = __builtin_amdgcn_mfma_f32_16x16x32_bf16(
                        af[am], bf[nf], acc[am][nf], 0, 0, 0);
        }
        __syncthreads();                           // all reads done before restage
    }

    float bia[4];
#pragma unroll
    for (int nf = 0; nf < 4; ++nf) bia[nf] = bias[bn + wn + nf * 16 + lr];

#pragma unroll
    for (int am = 0; am < 4; ++am)
#pragma unroll
        for (int nf = 0; nf < 4; ++nf) {
            if (OUTMODE == 2) {
                int mbase = bm + wm + am * 16 + lg * 4;     // = b*SS + s_base
                int n = bn + wn + nf * 16 + lr;
                int bidx = mbase >> 11, sidx = mbase & (SS - 1);
                s16x4 o;
#pragma unroll
                for (int r = 0; r < 4; ++r)
                    o[r] = (short)f2b((acc[am][nf][r] + bia[nf]) * alpha);
                *(s16x4*)((unsigned short*)Y +
                          (((size_t)(bidx << 10) + n) << 11) + sidx) = o;
            } else {
#pragma unroll
                for (int r = 0; r < 4; ++r) {
                    float o = (acc[am][nf][r] + bia[nf]) * alpha;
                    size_t m = (size_t)(bm + wm + am * 16 + lg * 4 + r);
                    size_t n = (size_t)(bn + wn + nf * 16 + lr);
                    if (OUTMODE == 1) ((unsigned short*)Y)[m * N + n] = f2b(o);
                    else              ((float*)Y)[m * N + n] = o;
                }
            }
        }
}

// ---------------------------------------------------------------------------
// Per-query band bounds via binary search (timestamps sorted per sequence).
// ---------------------------------------------------------------------------
__global__ __launch_bounds__(256)
void band_bounds(const float* __restrict__ ts, int* __restrict__ lo, int* __restrict__ hi)
{
    int idx = blockIdx.x * 256 + threadIdx.x;
    if (idx >= NN) return;
    int b = idx / SS, q = idx % SS;
    const float* t = ts + (size_t)b * SS;
    float tq = t[q];
    float lot = tq - WINDOWF - 1.0f;
    float hit = tq + WINDOWF + 1.0f;
    int l = 0, r = q;
    while (l < r) { int m = (l + r) >> 1; if (t[m] < lot) l = m + 1; else r = m; }
    lo[idx] = l;
    int l2 = q, r2 = SS - 1;
    while (l2 < r2) { int m = (l2 + r2 + 1) >> 1; if (t[m] > hit) r2 = m - 1; else l2 = m; }
    hi[idx] = l2;
}

// ---------------------------------------------------------------------------
// MFMA flash attention, round-8:
//  - 64-row q-tiles -> 2048 blocks (vs 512): ~2.5x more resident waves/CU.
//  - K/V staged by global_load_lds (w=16) into DOUBLE-buffered LDS with
//    pre-swizzled source; 1 barrier/tile: {issue t+1 -> compute t -> barrier}.
//  - chunk-XOR (^= row&7) read swizzle: conflict-free QK b128 / PV b64 reads.
//  - defer-max (T13, THR=8 log2): skip O/l rescale when tile max is small.
//  - swapped QK^T (lane-local softmax), in-register P via cvt_pk, permuted-k PV.
// ---------------------------------------------------------------------------
__global__ __launch_bounds__(256)
void attn_mfma(const unsigned short* __restrict__ Qb, const unsigned short* __restrict__ Kb,
               const unsigned short* __restrict__ Vt, const float* __restrict__ Tg,
               const int* __restrict__ lo, const int* __restrict__ hi,
               unsigned short* __restrict__ Ab)
{
    __shared__ unsigned short Ks[2][64 * 64];   // [key][dim], chunk-swizzled
    __shared__ unsigned short Vs[2][64 * 64];   // [dim][key], chunk-swizzled

    // XCD-aware decode: each XCD owns 8 (b,h) pairs; 32 q-tiles each.
    const int blk = blockIdx.x;
    const int xcd = blk & 7;
    const int idx = blk >> 3;              // 0..255
    const int bh  = xcd * 8 + (idx >> 5);
    const int qt  = idx & 31;
    const int b = bh >> 4, h = bh & 15;

    const int tid = threadIdx.x;
    const int wid = tid >> 6, l = tid & 63;
    const int lr = l & 15, lg = l >> 4;
    const int q0w = qt * 64 + wid * 16;

    const size_t qrow = (size_t)(b * SS + q0w + lr);
    const bf16x8 qf0 = *(const bf16x8*)(Qb + qrow * DD + h * HDD + lg * 8);
    const bf16x8 qf1 = *(const bf16x8*)(Qb + qrow * DD + h * HDD + 32 + lg * 8);

    const float* tb = Tg + (size_t)b * SS;
    const float tq = tb[q0w + lr];
    const float tq_min = tb[qt * 64];
    const float tq_max = tb[qt * 64 + 63];

    const int t0 = lo[b * SS + qt * 64] >> 6;
    const int t1 = hi[b * SS + qt * 64 + 63] >> 6;

    const unsigned short* Kbh = Kb + (size_t)b * SS * DD + h * HDD;
    const unsigned short* Vth = Vt + ((size_t)(b * 1024 + h * HDD)) * SS;

    // staging lane map (per gload instr: 8 rows x 8 chunks)
    const int srow = l >> 3;
    const int schunk = ((l & 7) ^ srow) * 8;

    float m_ = -1e30f, l_ = 0.f;
    f32x4 o_[4];
#pragma unroll
    for (int df = 0; df < 4; ++df) o_[df] = (f32x4){0.f, 0.f, 0.f, 0.f};

    // prologue: stage tile t0 into buffer 0 (wave wid -> row-groups 2wid,2wid+1)
#pragma unroll
    for (int i = 0; i < 2; ++i) {
        const int r0 = (wid * 2 + i) * 8;
        gload16(Kbh + (size_t)(t0 * 64 + r0 + srow) * DD + schunk, &Ks[0][r0 * 64]);
        gload16(Vth + (size_t)(r0 + srow) * SS + t0 * 64 + schunk, &Vs[0][r0 * 64]);
    }
    __syncthreads();

    int cur = 0;
    for (int t = t0; t <= t1; ++t) {
        const int kk0 = t * 64;

        // ---- issue next tile's staging into the other buffer ----
        if (t < t1) {
            const int kn = kk0 + 64;
#pragma unroll
            for (int i = 0; i < 2; ++i) {
                const int r0 = (wid * 2 + i) * 8;
                gload16(Kbh + (size_t)(kn + r0 + srow) * DD + schunk, &Ks[cur ^ 1][r0 * 64]);
                gload16(Vth + (size_t)(r0 + srow) * SS + kn + schunk, &Vs[cur ^ 1][r0 * 64]);
            }
        }

        // ---- QK^T from LDS (swizzled reads) ----
        f32x4 s[4];
        __builtin_amdgcn_s_setprio(1);
#pragma unroll
        for (int kf = 0; kf < 4; ++kf) {
            const int r = kf * 16 + lr;
            const int x = r & 7;
            bf16x8 ka0 = *(const bf16x8*)&Ks[cur][r * 64 + ((lg ^ x) * 8)];
            bf16x8 ka1 = *(const bf16x8*)&Ks[cur][r * 64 + (((4 + lg) ^ x) * 8)];
            f32x4 z = (f32x4){0.f, 0.f, 0.f, 0.f};
            z = __builtin_amdgcn_mfma_f32_16x16x32_bf16(ka0, qf0, z, 0, 0, 0);
            z = __builtin_amdgcn_mfma_f32_16x16x32_bf16(ka1, qf1, z, 0, 0, 0);
            s[kf] = z;
        }
        __builtin_amdgcn_s_setprio(0);

        // ---- exact mask only on boundary tiles ----
        const bool needmask = !((tq_max - tb[kk0] <= WINDOWF - 4.0f) &&
                                (tb[kk0 + 63] - tq_min <= WINDOWF - 4.0f));
        if (needmask) {
#pragma unroll
            for (int kf = 0; kf < 4; ++kf) {
                float4 tk4 = *(const float4*)(tb + kk0 + kf * 16 + lg * 4);
                if (!(fabsf(tq - tk4.x) <= WINDOWF)) s[kf][0] = -INFINITY;
                if (!(fabsf(tq - tk4.y) <= WINDOWF)) s[kf][1] = -INFINITY;
                if (!(fabsf(tq - tk4.z) <= WINDOWF)) s[kf][2] = -INFINITY;
                if (!(fabsf(tq - tk4.w) <= WINDOWF)) s[kf][3] = -INFINITY;
            }
        }

        // ---- online softmax with defer-max ----
        float mt = s[0][0];
#pragma unroll
        for (int kf = 0; kf < 4; ++kf)
#pragma unroll
            for (int r = 0; r < 4; ++r) mt = fmaxf(mt, s[kf][r]);
        mt = fmaxf(mt, __shfl_xor(mt, 16));
        mt = fmaxf(mt, __shfl_xor(mt, 32));
        if (!__all(mt <= m_ + 8.0f)) {
            const float mn = fmaxf(m_, mt);
            const float f_ = __builtin_amdgcn_exp2f(m_ - mn);
            l_ *= f_;
#pragma unroll
            for (int df = 0; df < 4; ++df)
#pragma unroll
                for (int r = 0; r < 4; ++r) o_[df][r] *= f_;
            m_ = mn;
        }
        float rs = 0.f;
#pragma unroll
        for (int kf = 0; kf < 4; ++kf)
#pragma unroll
            for (int r = 0; r < 4; ++r) {
                float p = __builtin_amdgcn_exp2f(s[kf][r] - m_);
                s[kf][r] = p;
                rs += p;
            }
        rs += __shfl_xor(rs, 16);
        rs += __shfl_xor(rs, 32);
        l_ += rs;

        // ---- P^T -> packed bf16 (in-register) ----
        union { unsigned int u[4]; bf16x8 v; } pb[2];
#pragma unroll
        for (int c = 0; c < 2; ++c) {
            pb[c].u[0] = cvt_pk_bf16(s[2 * c][0],     s[2 * c][1]);
            pb[c].u[1] = cvt_pk_bf16(s[2 * c][2],     s[2 * c][3]);
            pb[c].u[2] = cvt_pk_bf16(s[2 * c + 1][0], s[2 * c + 1][1]);
            pb[c].u[3] = cvt_pk_bf16(s[2 * c + 1][2], s[2 * c + 1][3]);
        }

        // ---- O^T += V^T . P^T from LDS (swizzled b64 reads) ----
        __builtin_amdgcn_s_setprio(1);
#pragma unroll
        for (int df = 0; df < 4; ++df) {
            const int d = df * 16 + lr;
            const int x = d & 7;
            const int base = d * 64;
            const int w = (lg & 1) * 4;            // within-chunk elem offset
#pragma unroll
            for (int c = 0; c < 2; ++c) {
                union { bf16x4 hh[2]; bf16x8 v; } va;
                va.hh[0] = *(const bf16x4*)&Vs[cur][base + (((4 * c +     (lg >> 1)) ^ x) * 8) + w];
                va.hh[1] = *(const bf16x4*)&Vs[cur][base + (((4 * c + 2 + (lg >> 1)) ^ x) * 8) + w];
                o_[df] = __builtin_amdgcn_mfma_f32_16x16x32_bf16(va.v, pb[c].v, o_[df], 0, 0, 0);
            }
        }
        __builtin_amdgcn_s_setprio(0);

        __syncthreads();     // drains t+1 staging vmcnt; all reads of cur done
        cur ^= 1;
    }

    // finalize: attended[q][d] = O^T / l, packed 8B stores
    const float inv = 1.f / l_;
#pragma unroll
    for (int df = 0; df < 4; ++df) {
        s16x4 o;
#pragma unroll
        for (int r = 0; r < 4; ++r) o[r] = (short)f2b(o_[df][r] * inv);
        *(s16x4*)(Ab + qrow * DD + h * HDD + df * 16 + lg * 4) = o;
    }
}

// ---------------------------------------------------------------------------
// change_scores[n] = out[n,:] . Wc + bc   (one wave per row)
// ---------------------------------------------------------------------------
__global__ __launch_bounds__(256)
void change_kernel(const float* __restrict__ out, const float* __restrict__ Wc,
                   const float* __restrict__ bc, float* __restrict__ cs)
{
    int row = blockIdx.x * 4 + (threadIdx.x >> 6);
    int lane = threadIdx.x & 63;
    const float* o = out + (size_t)row * DD;
    float sum = 0.f;
#pragma unroll
    for (int k = 0; k < DD / 256; ++k) {
        int c = lane * 4 + k * 256;
        float4 v = *(const float4*)(o + c);
        float4 w = *(const float4*)(Wc + c);
        sum += v.x * w.x + v.y * w.y + v.z * w.z + v.w * w.w;
    }
#pragma unroll
    for (int off = 1; off < 64; off <<= 1) sum += __shfl_xor(sum, off);
    if (lane == 0) cs[row] = sum + bc[0];
}

// ---------------------------------------------------------------------------
extern "C" void kernel_launch(void* const* d_in, const int* in_sizes, int n_in,
                              void* d_out, int out_size, void* d_ws, size_t ws_size,
                              hipStream_t stream)
{
    (void)in_sizes; (void)n_in; (void)out_size; (void)ws_size;
    const float* x  = (const float*)d_in[0];
    const float* ts = (const float*)d_in[1];
    const float* Wq = (const float*)d_in[2];
    const float* bq = (const float*)d_in[3];
    const float* Wk = (const float*)d_in[4];
    const float* bk = (const float*)d_in[5];
    const float* Wv = (const float*)d_in[6];
    const float* bv = (const float*)d_in[7];
    const float* Wo = (const float*)d_in[8];
    const float* bo = (const float*)d_in[9];
    const float* Wc = (const float*)d_in[10];
    const float* bc = (const float*)d_in[11];

    float* out = (float*)d_out;                 // [N*D] output, then [N] change scores

    unsigned short* xb  = (unsigned short*)d_ws;
    unsigned short* Qb  = xb  + (size_t)NN * DD;
    unsigned short* Kb2 = Qb  + (size_t)NN * DD;
    unsigned short* Vtb = Kb2 + (size_t)NN * DD;   // transposed [b][h*64+d][s]
    unsigned short* Abf = Vtb + (size_t)NN * DD;
    unsigned short* Wqb = Abf + (size_t)NN * DD;
    unsigned short* Wkb = Wqb + (size_t)DD * DD;
    unsigned short* Wvb = Wkb + (size_t)DD * DD;
    unsigned short* Wob = Wvb + (size_t)DD * DD;
    int* lo = (int*)(Wob + (size_t)DD * DD);
    int* hi = lo + NN;

    // converts
    cvt_bf16<<<(NN * DD / 4 + 255) / 256, 256, 0, stream>>>(x, xb, NN * DD);
    cvt_bf16<<<(DD * DD / 4 + 255) / 256, 256, 0, stream>>>(Wq, Wqb, DD * DD);
    cvt_bf16<<<(DD * DD / 4 + 255) / 256, 256, 0, stream>>>(Wk, Wkb, DD * DD);
    cvt_bf16<<<(DD * DD / 4 + 255) / 256, 256, 0, stream>>>(Wv, Wvb, DD * DD);
    cvt_bf16<<<(DD * DD / 4 + 255) / 256, 256, 0, stream>>>(Wo, Wob, DD * DD);

    dim3 g(NN / 128, DD / 128);
    gemm_bf16<1><<<g, 256, 0, stream>>>(xb, Wqb, bq, Qb,  NN, DD, DD, SCALE2);
    gemm_bf16<1><<<g, 256, 0, stream>>>(xb, Wkb, bk, Kb2, NN, DD, DD, 1.0f);
    gemm_bf16<2><<<g, 256, 0, stream>>>(xb, Wvb, bv, Vtb, NN, DD, DD, 1.0f);
    band_bounds<<<NN / 256, 256, 0, stream>>>(ts, lo, hi);
    attn_mfma<<<BB * HH * (SS / 64), 256, 0, stream>>>(Qb, Kb2, Vtb, ts, lo, hi, Abf);
    gemm_bf16<0><<<g, 256, 0, stream>>>(Abf, Wob, bo, out, NN, DD, DD, 1.0f);
    change_kernel<<<NN / 4, 256, 0, stream>>>(out, Wc, bc, out + (size_t)NN * DD);
}

// Round 9
// 195.637 us; speedup vs baseline: 2.5610x; 1.0446x over previous
//
#include <hip/hip_runtime.h>
#include <math.h>

#define BB 4
#define SS 2048
#define DD 1024
#define HH 16
#define HDD 64
#define NN (BB*SS)            // 8192 rows
#define WINDOWF 604800.0f     // 7 days
#define LOG2E 1.44269504088896340736f
#define SCALE2 (0.125f * LOG2E)   // 1/sqrt(64) * log2(e): scores in log2 domain

typedef __attribute__((ext_vector_type(8))) short bf16x8;
typedef __attribute__((ext_vector_type(4))) short bf16x4;
typedef __attribute__((ext_vector_type(4))) short s16x4;
typedef __attribute__((ext_vector_type(4))) float f32x4;

__device__ __forceinline__ unsigned short f2b(float f) {
    unsigned int x = __float_as_uint(f);
    unsigned int r = x + 0x7FFFu + ((x >> 16) & 1u);
    return (unsigned short)(r >> 16);
}

__device__ __forceinline__ unsigned int cvt_pk_bf16(float lo, float hi) {
    unsigned int r;
    asm("v_cvt_pk_bf16_f32 %0, %1, %2" : "=v"(r) : "v"(lo), "v"(hi));
    return r;
}

// async global->LDS, 16B per lane; LDS dest = wave-uniform base + lane*16
__device__ __forceinline__ void gload16(const unsigned short* g, unsigned short* l) {
    __builtin_amdgcn_global_load_lds(
        (const __attribute__((address_space(1))) unsigned int*)g,
        (__attribute__((address_space(3))) unsigned int*)l, 16, 0, 0);
}

// ---------------------------------------------------------------------------
// Fused f32->bf16 converts (x, Wq, Wk, Wv, Wo) + band_bounds, one launch.
// grid.x = 8192 (x) + 4*1024 (weights) + 32 (band) = 12320 blocks of 256.
// ---------------------------------------------------------------------------
__global__ __launch_bounds__(256)
void cvt_band(const float* __restrict__ x,
              const float* __restrict__ Wq, const float* __restrict__ Wk,
              const float* __restrict__ Wv, const float* __restrict__ Wo,
              const float* __restrict__ ts,
              unsigned short* __restrict__ xb,
              unsigned short* __restrict__ Wqb, unsigned short* __restrict__ Wkb,
              unsigned short* __restrict__ Wvb, unsigned short* __restrict__ Wob,
              int* __restrict__ lo, int* __restrict__ hi)
{
    const int g = blockIdx.x;
    const int tid = threadIdx.x;
    if (g < 12288) {
        const float* src; unsigned short* dst; int i;
        if (g < 8192) { src = x; dst = xb; i = g * 1024 + tid * 4; }
        else {
            const int wi = (g - 8192) >> 10;
            src = (wi == 0) ? Wq : (wi == 1) ? Wk : (wi == 2) ? Wv : Wo;
            dst = (wi == 0) ? Wqb : (wi == 1) ? Wkb : (wi == 2) ? Wvb : Wob;
            i = ((g - 8192) & 1023) * 1024 + tid * 4;
        }
        float4 v = *(const float4*)(src + i);
        s16x4 o;
        o[0] = (short)f2b(v.x); o[1] = (short)f2b(v.y);
        o[2] = (short)f2b(v.z); o[3] = (short)f2b(v.w);
        *(s16x4*)(dst + i) = o;
    } else {
        const int idx = (g - 12288) * 256 + tid;   // 0..8191
        const int b = idx / SS, q = idx % SS;
        const float* t = ts + (size_t)b * SS;
        float tq = t[q];
        float lot = tq - WINDOWF - 1.0f;
        float hit = tq + WINDOWF + 1.0f;
        int l = 0, r = q;
        while (l < r) { int m = (l + r) >> 1; if (t[m] < lot) l = m + 1; else r = m; }
        lo[idx] = l;
        int l2 = q, r2 = SS - 1;
        while (l2 < r2) { int m = (l2 + r2 + 1) >> 1; if (t[m] > hit) r2 = m - 1; else l2 = m; }
        hi[idx] = l2;
    }
}

// ---------------------------------------------------------------------------
// bf16 MFMA GEMM, m97 structure: BK=64, global_load_lds w=16 staging with
// pre-swizzled SOURCE (chunk ^= row&7) + swizzled ds_read (conflict-free),
// 2-barrier K-loop.  Y = (A @ Bw^T + bias) * alpha.
// OUTMODE: 0 = f32 row-major, 1 = bf16 row-major,
//          2 = bf16 transposed Vt layout [b][channel][s] (channel = h*64+d)
// ---------------------------------------------------------------------------
template<int OUTMODE>
__global__ __launch_bounds__(256)
void gemm_bf16(const unsigned short* __restrict__ A,
               const unsigned short* __restrict__ Bw,
               const float* __restrict__ bias,
               void* __restrict__ Y, int M, int N, int K, float alpha)
{
    constexpr int BM = 128, BN = 128, BK = 64;
    __shared__ unsigned short As[BM * BK];    // [row][64 elems], chunk-swizzled
    __shared__ unsigned short Bs[BN * BK];

    const int bm = blockIdx.x * BM;
    const int bn = blockIdx.y * BN;
    const int tid = threadIdx.x;
    const int wid = tid >> 6, l = tid & 63;
    const int wm = (wid >> 1) * 64, wn = (wid & 1) * 64;
    const int lr = l & 15, lg = l >> 4;

    // staging lane map: 8 lanes/row-chunk; src chunk pre-swizzled
    const int srow = l >> 3;                       // 0..7 within 8-row group
    const int schunk = ((l & 7) ^ srow) * 8;       // elem offset in row

    f32x4 acc[4][4];
#pragma unroll
    for (int i = 0; i < 4; ++i)
#pragma unroll
        for (int j = 0; j < 4; ++j) acc[i][j] = (f32x4){0.f, 0.f, 0.f, 0.f};

    for (int k0 = 0; k0 < K; k0 += BK) {
#pragma unroll
        for (int i = 0; i < 4; ++i) {
            const int r0 = wid * 32 + i * 8;
            gload16(A  + (size_t)(bm + r0 + srow) * K + k0 + schunk, &As[r0 * BK]);
            gload16(Bw + (size_t)(bn + r0 + srow) * K + k0 + schunk, &Bs[r0 * BK]);
        }
        __syncthreads();                           // vmcnt drained -> LDS ready

#pragma unroll
        for (int ks = 0; ks < 2; ++ks) {
            bf16x8 af[4], bf[4];
#pragma unroll
            for (int am = 0; am < 4; ++am) {
                const int row = wm + am * 16 + lr;
                af[am] = *(const bf16x8*)&As[row * BK + (((ks * 4 + lg) ^ (row & 7)) * 8)];
            }
#pragma unroll
            for (int nf = 0; nf < 4; ++nf) {
                const int row = wn + nf * 16 + lr;
                bf[nf] = *(const bf16x8*)&Bs[row * BK + (((ks * 4 + lg) ^ (row & 7)) * 8)];
            }
#pragma unroll
            for (int am = 0; am < 4; ++am)
#pragma unroll
                for (int nf = 0; nf < 4; ++nf)
                    acc[am][nf] = __builtin_amdgcn_mfma_f32_16x16x32_bf16(
                        af[am], bf[nf], acc[am][nf], 0, 0, 0);
        }
        __syncthreads();                           // all reads done before restage
    }

    float bia[4];
#pragma unroll
    for (int nf = 0; nf < 4; ++nf) bia[nf] = bias[bn + wn + nf * 16 + lr];

#pragma unroll
    for (int am = 0; am < 4; ++am)
#pragma unroll
        for (int nf = 0; nf < 4; ++nf) {
            if (OUTMODE == 2) {
                int mbase = bm + wm + am * 16 + lg * 4;     // = b*SS + s_base
                int n = bn + wn + nf * 16 + lr;
                int bidx = mbase >> 11, sidx = mbase & (SS - 1);
                s16x4 o;
#pragma unroll
                for (int r = 0; r < 4; ++r)
                    o[r] = (short)f2b((acc[am][nf][r] + bia[nf]) * alpha);
                *(s16x4*)((unsigned short*)Y +
                          (((size_t)(bidx << 10) + n) << 11) + sidx) = o;
            } else {
#pragma unroll
                for (int r = 0; r < 4; ++r) {
                    float o = (acc[am][nf][r] + bia[nf]) * alpha;
                    size_t m = (size_t)(bm + wm + am * 16 + lg * 4 + r);
                    size_t n = (size_t)(bn + wn + nf * 16 + lr);
                    if (OUTMODE == 1) ((unsigned short*)Y)[m * N + n] = f2b(o);
                    else              ((float*)Y)[m * N + n] = o;
                }
            }
        }
}

// ---------------------------------------------------------------------------
// MFMA flash attention, round-9: R8 structure (64q tiles, dbuf gload_lds,
// chunk-XOR swizzle, defer-max, swapped QK, permuted-k PV) with the VALU
// diet: all LDS read offsets precomputed per-lane (loop-invariant; chunk
// XORs fold to ^32/^16/^48 byte deltas), ping-pong LDS pointers swapped at
// loop end, staging global pointers advanced by constant stride.
// ---------------------------------------------------------------------------
__global__ __launch_bounds__(256)
void attn_mfma(const unsigned short* __restrict__ Qb, const unsigned short* __restrict__ Kb,
               const unsigned short* __restrict__ Vt, const float* __restrict__ Tg,
               const int* __restrict__ lo, const int* __restrict__ hi,
               unsigned short* __restrict__ Ab)
{
    __shared__ unsigned short Ks[2][64 * 64];   // [key][dim], chunk-swizzled
    __shared__ unsigned short Vs[2][64 * 64];   // [dim][key], chunk-swizzled

    // XCD-aware decode: each XCD owns 8 (b,h) pairs; 32 q-tiles each.
    const int blk = blockIdx.x;
    const int xcd = blk & 7;
    const int idx = blk >> 3;              // 0..255
    const int bh  = xcd * 8 + (idx >> 5);
    const int qt  = idx & 31;
    const int b = bh >> 4, h = bh & 15;

    const int tid = threadIdx.x;
    const int wid = tid >> 6, l = tid & 63;
    const int lr = l & 15, lg = l >> 4;
    const int q0w = qt * 64 + wid * 16;

    const size_t qrow = (size_t)(b * SS + q0w + lr);
    const bf16x8 qf0 = *(const bf16x8*)(Qb + qrow * DD + h * HDD + lg * 8);
    const bf16x8 qf1 = *(const bf16x8*)(Qb + qrow * DD + h * HDD + 32 + lg * 8);

    const float* tb = Tg + (size_t)b * SS;
    const float tq = tb[q0w + lr];
    const float tq_min = tb[qt * 64];
    const float tq_max = tb[qt * 64 + 63];

    const int t0 = lo[b * SS + qt * 64] >> 6;
    const int t1 = hi[b * SS + qt * 64 + 63] >> 6;

    const unsigned short* Kbh = Kb + (size_t)b * SS * DD + h * HDD;
    const unsigned short* Vth = Vt + ((size_t)(b * 1024 + h * HDD)) * SS;

    // staging lane map (per gload instr: 8 rows x 8 chunks), src pre-swizzled
    const int srow = l >> 3;
    const int schunk = ((l & 7) ^ srow) * 8;

    // persistent staging pointers (advance by constant per tile)
    const unsigned short* kg0 = Kbh + (size_t)(t0 * 64 + wid * 16 + srow) * DD + schunk;
    const unsigned short* kg1 = kg0 + 8 * DD;
    const unsigned short* vg0 = Vth + (size_t)(wid * 16 + srow) * SS + t0 * 64 + schunk;
    const unsigned short* vg1 = vg0 + 8 * SS;

    // loop-invariant per-lane read offsets (elems)
    const int x = lr & 7;
    const int ka_off = lr * 64 + ((lg ^ x) << 3);              // QK: +kf*1024, hi half ^32
    const int w = (lg & 1) * 4;
    const int pvA = lr * 64 + ((((lg >> 1) ^ x)) << 3) + w;    // PV: +df*1024
    const int pvB = pvA ^ 16;
    const int pvC = pvA ^ 32;
    const int pvD = pvA ^ 48;

    unsigned short *Kc = &Ks[0][0], *Kn = &Ks[1][0];
    unsigned short *Vc = &Vs[0][0], *Vn = &Vs[1][0];
    unsigned short *KnW = Kn, *VnW = Vn;   // wave-uniform write bases updated by swap

    float m_ = -1e30f, l_ = 0.f;
    f32x4 o_[4];
#pragma unroll
    for (int df = 0; df < 4; ++df) o_[df] = (f32x4){0.f, 0.f, 0.f, 0.f};

    // prologue: stage tile t0 into buffer 0
    gload16(kg0, Kc + wid * 1024);
    gload16(kg1, Kc + wid * 1024 + 512);
    gload16(vg0, Vc + wid * 1024);
    gload16(vg1, Vc + wid * 1024 + 512);
    kg0 += 64 * DD; kg1 += 64 * DD; vg0 += 64; vg1 += 64;
    __syncthreads();

    for (int t = t0; t <= t1; ++t) {
        const int kk0 = t * 64;

        // ---- issue next tile's staging into the other buffer ----
        if (t < t1) {
            gload16(kg0, Kn + wid * 1024);
            gload16(kg1, Kn + wid * 1024 + 512);
            gload16(vg0, Vn + wid * 1024);
            gload16(vg1, Vn + wid * 1024 + 512);
            kg0 += 64 * DD; kg1 += 64 * DD; vg0 += 64; vg1 += 64;
        }

        // ---- QK^T from LDS (precomputed offsets) ----
        f32x4 s[4];
        __builtin_amdgcn_s_setprio(1);
#pragma unroll
        for (int kf = 0; kf < 4; ++kf) {
            bf16x8 ka0 = *(const bf16x8*)(Kc + kf * 1024 + ka_off);
            bf16x8 ka1 = *(const bf16x8*)(Kc + kf * 1024 + (ka_off ^ 32));
            f32x4 z = (f32x4){0.f, 0.f, 0.f, 0.f};
            z = __builtin_amdgcn_mfma_f32_16x16x32_bf16(ka0, qf0, z, 0, 0, 0);
            z = __builtin_amdgcn_mfma_f32_16x16x32_bf16(ka1, qf1, z, 0, 0, 0);
            s[kf] = z;
        }
        __builtin_amdgcn_s_setprio(0);

        // ---- exact mask only on boundary tiles ----
        const bool needmask = !((tq_max - tb[kk0] <= WINDOWF - 4.0f) &&
                                (tb[kk0 + 63] - tq_min <= WINDOWF - 4.0f));
        if (needmask) {
#pragma unroll
            for (int kf = 0; kf < 4; ++kf) {
                float4 tk4 = *(const float4*)(tb + kk0 + kf * 16 + lg * 4);
                if (!(fabsf(tq - tk4.x) <= WINDOWF)) s[kf][0] = -INFINITY;
                if (!(fabsf(tq - tk4.y) <= WINDOWF)) s[kf][1] = -INFINITY;
                if (!(fabsf(tq - tk4.z) <= WINDOWF)) s[kf][2] = -INFINITY;
                if (!(fabsf(tq - tk4.w) <= WINDOWF)) s[kf][3] = -INFINITY;
            }
        }

        // ---- online softmax with defer-max ----
        float mt = s[0][0];
#pragma unroll
        for (int kf = 0; kf < 4; ++kf)
#pragma unroll
            for (int r = 0; r < 4; ++r) mt = fmaxf(mt, s[kf][r]);
        mt = fmaxf(mt, __shfl_xor(mt, 16));
        mt = fmaxf(mt, __shfl_xor(mt, 32));
        if (!__all(mt <= m_ + 8.0f)) {
            const float mn = fmaxf(m_, mt);
            const float f_ = __builtin_amdgcn_exp2f(m_ - mn);
            l_ *= f_;
#pragma unroll
            for (int df = 0; df < 4; ++df)
#pragma unroll
                for (int r = 0; r < 4; ++r) o_[df][r] *= f_;
            m_ = mn;
        }
        float rs = 0.f;
#pragma unroll
        for (int kf = 0; kf < 4; ++kf)
#pragma unroll
            for (int r = 0; r < 4; ++r) {
                float p = __builtin_amdgcn_exp2f(s[kf][r] - m_);
                s[kf][r] = p;
                rs += p;
            }
        rs += __shfl_xor(rs, 16);
        rs += __shfl_xor(rs, 32);
        l_ += rs;

        // ---- P^T -> packed bf16 (in-register) ----
        union { unsigned int u[4]; bf16x8 v; } pb[2];
#pragma unroll
        for (int c = 0; c < 2; ++c) {
            pb[c].u[0] = cvt_pk_bf16(s[2 * c][0],     s[2 * c][1]);
            pb[c].u[1] = cvt_pk_bf16(s[2 * c][2],     s[2 * c][3]);
            pb[c].u[2] = cvt_pk_bf16(s[2 * c + 1][0], s[2 * c + 1][1]);
            pb[c].u[3] = cvt_pk_bf16(s[2 * c + 1][2], s[2 * c + 1][3]);
        }

        // ---- O^T += V^T . P^T from LDS (precomputed offsets) ----
        __builtin_amdgcn_s_setprio(1);
#pragma unroll
        for (int df = 0; df < 4; ++df) {
            const int base = df * 1024;
            union { bf16x4 hh[2]; bf16x8 v; } va0, va1;
            va0.hh[0] = *(const bf16x4*)(Vc + base + pvA);
            va0.hh[1] = *(const bf16x4*)(Vc + base + pvB);
            va1.hh[0] = *(const bf16x4*)(Vc + base + pvC);
            va1.hh[1] = *(const bf16x4*)(Vc + base + pvD);
            o_[df] = __builtin_amdgcn_mfma_f32_16x16x32_bf16(va0.v, pb[0].v, o_[df], 0, 0, 0);
            o_[df] = __builtin_amdgcn_mfma_f32_16x16x32_bf16(va1.v, pb[1].v, o_[df], 0, 0, 0);
        }
        __builtin_amdgcn_s_setprio(0);

        __syncthreads();     // drains staging vmcnt; all reads of cur done
        unsigned short* tk = Kc; Kc = Kn; Kn = tk;
        unsigned short* tv = Vc; Vc = Vn; Vn = tv;
        (void)KnW; (void)VnW;
    }

    // finalize: attended[q][d] = O^T / l, packed 8B stores
    const float inv = 1.f / l_;
#pragma unroll
    for (int df = 0; df < 4; ++df) {
        s16x4 o;
#pragma unroll
        for (int r = 0; r < 4; ++r) o[r] = (short)f2b(o_[df][r] * inv);
        *(s16x4*)(Ab + qrow * DD + h * HDD + df * 16 + lg * 4) = o;
    }
}

// ---------------------------------------------------------------------------
// change_scores[n] = out[n,:] . Wc + bc   (one wave per row)
// ---------------------------------------------------------------------------
__global__ __launch_bounds__(256)
void change_kernel(const float* __restrict__ out, const float* __restrict__ Wc,
                   const float* __restrict__ bc, float* __restrict__ cs)
{
    int row = blockIdx.x * 4 + (threadIdx.x >> 6);
    int lane = threadIdx.x & 63;
    const float* o = out + (size_t)row * DD;
    float sum = 0.f;
#pragma unroll
    for (int k = 0; k < DD / 256; ++k) {
        int c = lane * 4 + k * 256;
        float4 v = *(const float4*)(o + c);
        float4 w = *(const float4*)(Wc + c);
        sum += v.x * w.x + v.y * w.y + v.z * w.z + v.w * w.w;
    }
#pragma unroll
    for (int off = 1; off < 64; off <<= 1) sum += __shfl_xor(sum, off);
    if (lane == 0) cs[row] = sum + bc[0];
}

// ---------------------------------------------------------------------------
extern "C" void kernel_launch(void* const* d_in, const int* in_sizes, int n_in,
                              void* d_out, int out_size, void* d_ws, size_t ws_size,
                              hipStream_t stream)
{
    (void)in_sizes; (void)n_in; (void)out_size; (void)ws_size;
    const float* x  = (const float*)d_in[0];
    const float* ts = (const float*)d_in[1];
    const float* Wq = (const float*)d_in[2];
    const float* bq = (const float*)d_in[3];
    const float* Wk = (const float*)d_in[4];
    const float* bk = (const float*)d_in[5];
    const float* Wv = (const float*)d_in[6];
    const float* bv = (const float*)d_in[7];
    const float* Wo = (const float*)d_in[8];
    const float* bo = (const float*)d_in[9];
    const float* Wc = (const float*)d_in[10];
    const float* bc = (const float*)d_in[11];

    float* out = (float*)d_out;                 // [N*D] output, then [N] change scores

    unsigned short* xb  = (unsigned short*)d_ws;
    unsigned short* Qb  = xb  + (size_t)NN * DD;
    unsigned short* Kb2 = Qb  + (size_t)NN * DD;
    unsigned short* Vtb = Kb2 + (size_t)NN * DD;   // transposed [b][h*64+d][s]
    unsigned short* Abf = Vtb + (size_t)NN * DD;
    unsigned short* Wqb = Abf + (size_t)NN * DD;
    unsigned short* Wkb = Wqb + (size_t)DD * DD;
    unsigned short* Wvb = Wkb + (size_t)DD * DD;
    unsigned short* Wob = Wvb + (size_t)DD * DD;
    int* lo = (int*)(Wob + (size_t)DD * DD);
    int* hi = lo + NN;

    // fused converts + band bounds (one launch)
    cvt_band<<<12320, 256, 0, stream>>>(x, Wq, Wk, Wv, Wo, ts,
                                        xb, Wqb, Wkb, Wvb, Wob, lo, hi);

    dim3 g(NN / 128, DD / 128);
    gemm_bf16<1><<<g, 256, 0, stream>>>(xb, Wqb, bq, Qb,  NN, DD, DD, SCALE2);
    gemm_bf16<1><<<g, 256, 0, stream>>>(xb, Wkb, bk, Kb2, NN, DD, DD, 1.0f);
    gemm_bf16<2><<<g, 256, 0, stream>>>(xb, Wvb, bv, Vtb, NN, DD, DD, 1.0f);
    attn_mfma<<<BB * HH * (SS / 64), 256, 0, stream>>>(Qb, Kb2, Vtb, ts, lo, hi, Abf);
    gemm_bf16<0><<<g, 256, 0, stream>>>(Abf, Wob, bo, out, NN, DD, DD, 1.0f);
    change_kernel<<<NN / 4, 256, 0, stream>>>(out, Wc, bc, out + (size_t)NN * DD);
}

// Round 10
// 190.218 us; speedup vs baseline: 2.6340x; 1.0285x over previous
//
#include <hip/hip_runtime.h>
#include <math.h>

#define BB 4
#define SS 2048
#define DD 1024
#define HH 16
#define HDD 64
#define NN (BB*SS)            // 8192 rows
#define WINDOWF 604800.0f     // 7 days
#define LOG2E 1.44269504088896340736f
#define SCALE2 (0.125f * LOG2E)   // 1/sqrt(64) * log2(e): scores in log2 domain

typedef __attribute__((ext_vector_type(8))) short bf16x8;
typedef __attribute__((ext_vector_type(4))) short bf16x4;
typedef __attribute__((ext_vector_type(4))) short s16x4;
typedef __attribute__((ext_vector_type(4))) float f32x4;

__device__ __forceinline__ unsigned short f2b(float f) {
    unsigned int x = __float_as_uint(f);
    unsigned int r = x + 0x7FFFu + ((x >> 16) & 1u);
    return (unsigned short)(r >> 16);
}

__device__ __forceinline__ unsigned int cvt_pk_bf16(float lo, float hi) {
    unsigned int r;
    asm("v_cvt_pk_bf16_f32 %0, %1, %2" : "=v"(r) : "v"(lo), "v"(hi));
    return r;
}

// async global->LDS, 16B per lane; LDS dest = wave-uniform base + lane*16
__device__ __forceinline__ void gload16(const unsigned short* g, unsigned short* l) {
    __builtin_amdgcn_global_load_lds(
        (const __attribute__((address_space(1))) unsigned int*)g,
        (__attribute__((address_space(3))) unsigned int*)l, 16, 0, 0);
}

// ---------------------------------------------------------------------------
// Fused f32->bf16 converts (x, Wq, Wk, Wv, Wo) + band_bounds, one launch.
// ---------------------------------------------------------------------------
__global__ __launch_bounds__(256)
void cvt_band(const float* __restrict__ x,
              const float* __restrict__ Wq, const float* __restrict__ Wk,
              const float* __restrict__ Wv, const float* __restrict__ Wo,
              const float* __restrict__ ts,
              unsigned short* __restrict__ xb,
              unsigned short* __restrict__ Wqb, unsigned short* __restrict__ Wkb,
              unsigned short* __restrict__ Wvb, unsigned short* __restrict__ Wob,
              int* __restrict__ lo, int* __restrict__ hi)
{
    const int g = blockIdx.x;
    const int tid = threadIdx.x;
    if (g < 12288) {
        const float* src; unsigned short* dst; int i;
        if (g < 8192) { src = x; dst = xb; i = g * 1024 + tid * 4; }
        else {
            const int wi = (g - 8192) >> 10;
            src = (wi == 0) ? Wq : (wi == 1) ? Wk : (wi == 2) ? Wv : Wo;
            dst = (wi == 0) ? Wqb : (wi == 1) ? Wkb : (wi == 2) ? Wvb : Wob;
            i = ((g - 8192) & 1023) * 1024 + tid * 4;
        }
        float4 v = *(const float4*)(src + i);
        s16x4 o;
        o[0] = (short)f2b(v.x); o[1] = (short)f2b(v.y);
        o[2] = (short)f2b(v.z); o[3] = (short)f2b(v.w);
        *(s16x4*)(dst + i) = o;
    } else {
        const int idx = (g - 12288) * 256 + tid;   // 0..8191
        const int b = idx / SS, q = idx % SS;
        const float* t = ts + (size_t)b * SS;
        float tq = t[q];
        float lot = tq - WINDOWF - 1.0f;
        float hit = tq + WINDOWF + 1.0f;
        int l = 0, r = q;
        while (l < r) { int m = (l + r) >> 1; if (t[m] < lot) l = m + 1; else r = m; }
        lo[idx] = l;
        int l2 = q, r2 = SS - 1;
        while (l2 < r2) { int m = (l2 + r2 + 1) >> 1; if (t[m] > hit) r2 = m - 1; else l2 = m; }
        hi[idx] = l2;
    }
}

// ---------------------------------------------------------------------------
// Shared GEMM body (m97 structure): BK=64, global_load_lds w=16 staging with
// pre-swizzled SOURCE (chunk ^= row&7) + swizzled ds_read, 2-barrier K-loop.
// outmode: 0 = f32 row-major, 1 = bf16 row-major, 2 = bf16 Vt [b][ch][s].
// ---------------------------------------------------------------------------
__device__ __forceinline__
void gemm_body(const unsigned short* __restrict__ A,
               const unsigned short* __restrict__ Bw,
               const float* __restrict__ bias,
               void* __restrict__ Y, int K, int Nout, float alpha,
               int outmode, int bm, int bn,
               unsigned short* As, unsigned short* Bs)
{
    constexpr int BK = 64;
    const int tid = threadIdx.x;
    const int wid = tid >> 6, l = tid & 63;
    const int wm = (wid >> 1) * 64, wn = (wid & 1) * 64;
    const int lr = l & 15, lg = l >> 4;

    const int srow = l >> 3;
    const int schunk = ((l & 7) ^ srow) * 8;

    f32x4 acc[4][4];
#pragma unroll
    for (int i = 0; i < 4; ++i)
#pragma unroll
        for (int j = 0; j < 4; ++j) acc[i][j] = (f32x4){0.f, 0.f, 0.f, 0.f};

    for (int k0 = 0; k0 < K; k0 += BK) {
#pragma unroll
        for (int i = 0; i < 4; ++i) {
            const int r0 = wid * 32 + i * 8;
            gload16(A  + (size_t)(bm + r0 + srow) * K + k0 + schunk, &As[r0 * BK]);
            gload16(Bw + (size_t)(bn + r0 + srow) * K + k0 + schunk, &Bs[r0 * BK]);
        }
        __syncthreads();

#pragma unroll
        for (int ks = 0; ks < 2; ++ks) {
            bf16x8 af[4], bf[4];
#pragma unroll
            for (int am = 0; am < 4; ++am) {
                const int row = wm + am * 16 + lr;
                af[am] = *(const bf16x8*)&As[row * BK + (((ks * 4 + lg) ^ (row & 7)) * 8)];
            }
#pragma unroll
            for (int nf = 0; nf < 4; ++nf) {
                const int row = wn + nf * 16 + lr;
                bf[nf] = *(const bf16x8*)&Bs[row * BK + (((ks * 4 + lg) ^ (row & 7)) * 8)];
            }
#pragma unroll
            for (int am = 0; am < 4; ++am)
#pragma unroll
                for (int nf = 0; nf < 4; ++nf)
                    acc[am][nf] = __builtin_amdgcn_mfma_f32_16x16x32_bf16(
                        af[am], bf[nf], acc[am][nf], 0, 0, 0);
        }
        __syncthreads();
    }

    float bia[4];
#pragma unroll
    for (int nf = 0; nf < 4; ++nf) bia[nf] = bias[bn + wn + nf * 16 + lr];

#pragma unroll
    for (int am = 0; am < 4; ++am)
#pragma unroll
        for (int nf = 0; nf < 4; ++nf) {
            if (outmode == 2) {
                int mbase = bm + wm + am * 16 + lg * 4;     // = b*SS + s_base
                int n = bn + wn + nf * 16 + lr;
                int bidx = mbase >> 11, sidx = mbase & (SS - 1);
                s16x4 o;
#pragma unroll
                for (int r = 0; r < 4; ++r)
                    o[r] = (short)f2b((acc[am][nf][r] + bia[nf]) * alpha);
                *(s16x4*)((unsigned short*)Y +
                          (((size_t)(bidx << 10) + n) << 11) + sidx) = o;
            } else {
#pragma unroll
                for (int r = 0; r < 4; ++r) {
                    float o = (acc[am][nf][r] + bia[nf]) * alpha;
                    size_t m = (size_t)(bm + wm + am * 16 + lg * 4 + r);
                    size_t n = (size_t)(bn + wn + nf * 16 + lr);
                    if (outmode == 1) ((unsigned short*)Y)[m * Nout + n] = f2b(o);
                    else              ((float*)Y)[m * Nout + n] = o;
                }
            }
        }
}

// Fused QKV projection: grid (M/128, 24); by>>3 selects {Q,K,V} segment.
__global__ __launch_bounds__(256)
void gemm_qkv(const unsigned short* __restrict__ xb,
              const unsigned short* __restrict__ Wqb,
              const unsigned short* __restrict__ Wkb,
              const unsigned short* __restrict__ Wvb,
              const float* __restrict__ bq, const float* __restrict__ bk,
              const float* __restrict__ bv,
              unsigned short* __restrict__ Qb, unsigned short* __restrict__ Kb2,
              unsigned short* __restrict__ Vtb)
{
    __shared__ unsigned short As[128 * 64];
    __shared__ unsigned short Bs[128 * 64];
    const int seg = blockIdx.y >> 3;
    const int bn = (blockIdx.y & 7) * 128;
    const unsigned short* Bw = (seg == 0) ? Wqb : (seg == 1) ? Wkb : Wvb;
    const float* bias = (seg == 0) ? bq : (seg == 1) ? bk : bv;
    void* Y = (seg == 0) ? (void*)Qb : (seg == 1) ? (void*)Kb2 : (void*)Vtb;
    const float alpha = (seg == 0) ? SCALE2 : 1.0f;
    const int outmode = (seg == 2) ? 2 : 1;
    gemm_body(xb, Bw, bias, Y, DD, DD, alpha, outmode,
              blockIdx.x * 128, bn, As, Bs);
}

// Output projection (f32 out).
__global__ __launch_bounds__(256)
void gemm_wo(const unsigned short* __restrict__ Abf,
             const unsigned short* __restrict__ Wob,
             const float* __restrict__ bo, float* __restrict__ out)
{
    __shared__ unsigned short As[128 * 64];
    __shared__ unsigned short Bs[128 * 64];
    gemm_body(Abf, Wob, bo, out, DD, DD, 1.0f, 0,
              blockIdx.x * 128, blockIdx.y * 128, As, Bs);
}

// ---------------------------------------------------------------------------
// MFMA flash attention, round-10: R9 structure with ROTATION swizzle
// (slot = (chunk + row) & 7) replacing XOR — same bijection discipline on
// staging source and both read sites, but consecutive lanes now round-robin
// bank groups -> conflict-free service order.  Plus max3 reduce tree.
// ---------------------------------------------------------------------------
__global__ __launch_bounds__(256)
void attn_mfma(const unsigned short* __restrict__ Qb, const unsigned short* __restrict__ Kb,
               const unsigned short* __restrict__ Vt, const float* __restrict__ Tg,
               const int* __restrict__ lo, const int* __restrict__ hi,
               unsigned short* __restrict__ Ab)
{
    __shared__ unsigned short Ks[2][64 * 64];   // [key][dim], rotation-swizzled
    __shared__ unsigned short Vs[2][64 * 64];   // [dim][key], rotation-swizzled

    // XCD-aware decode: each XCD owns 8 (b,h) pairs; 32 q-tiles each.
    const int blk = blockIdx.x;
    const int xcd = blk & 7;
    const int idx = blk >> 3;              // 0..255
    const int bh  = xcd * 8 + (idx >> 5);
    const int qt  = idx & 31;
    const int b = bh >> 4, h = bh & 15;

    const int tid = threadIdx.x;
    const int wid = tid >> 6, l = tid & 63;
    const int lr = l & 15, lg = l >> 4;
    const int q0w = qt * 64 + wid * 16;

    const size_t qrow = (size_t)(b * SS + q0w + lr);
    const bf16x8 qf0 = *(const bf16x8*)(Qb + qrow * DD + h * HDD + lg * 8);
    const bf16x8 qf1 = *(const bf16x8*)(Qb + qrow * DD + h * HDD + 32 + lg * 8);

    const float* tb = Tg + (size_t)b * SS;
    const float tq = tb[q0w + lr];
    const float tq_min = tb[qt * 64];
    const float tq_max = tb[qt * 64 + 63];

    const int t0 = lo[b * SS + qt * 64] >> 6;
    const int t1 = hi[b * SS + qt * 64 + 63] >> 6;

    const unsigned short* Kbh = Kb + (size_t)b * SS * DD + h * HDD;
    const unsigned short* Vth = Vt + ((size_t)(b * 1024 + h * HDD)) * SS;

    // staging lane map: slot p = l&7 holds chunk c = (p - row) & 7
    const int srow = l >> 3;
    const int schunk = (((l & 7) - srow) & 7) * 8;

    // persistent staging pointers (advance by constant per tile)
    const unsigned short* kg0 = Kbh + (size_t)(t0 * 64 + wid * 16 + srow) * DD + schunk;
    const unsigned short* kg1 = kg0 + 8 * DD;
    const unsigned short* vg0 = Vth + (size_t)(wid * 16 + srow) * SS + t0 * 64 + schunk;
    const unsigned short* vg1 = vg0 + 8 * SS;

    // loop-invariant read offsets (elems), rotation p = (chunk + row) & 7
    const int ka_off = lr * 64 + (((lg + lr) & 7) << 3);     // QK row lr, chunk lg
    const int c0 = lg >> 1, h4 = (lg & 1) * 4;               // PV row lr (mod16)
    const int pv0 = lr * 64 + (((c0 + 0 + lr) & 7) << 3) + h4;
    const int pv1 = lr * 64 + (((c0 + 2 + lr) & 7) << 3) + h4;
    const int pv2 = lr * 64 + (((c0 + 4 + lr) & 7) << 3) + h4;
    const int pv3 = lr * 64 + (((c0 + 6 + lr) & 7) << 3) + h4;

    unsigned short *Kc = &Ks[0][0], *Kn = &Ks[1][0];
    unsigned short *Vc = &Vs[0][0], *Vn = &Vs[1][0];

    float m_ = -1e30f, l_ = 0.f;
    f32x4 o_[4];
#pragma unroll
    for (int df = 0; df < 4; ++df) o_[df] = (f32x4){0.f, 0.f, 0.f, 0.f};

    // prologue: stage tile t0 into buffer 0
    gload16(kg0, Kc + wid * 1024);
    gload16(kg1, Kc + wid * 1024 + 512);
    gload16(vg0, Vc + wid * 1024);
    gload16(vg1, Vc + wid * 1024 + 512);
    kg0 += 64 * DD; kg1 += 64 * DD; vg0 += 64; vg1 += 64;
    __syncthreads();

    for (int t = t0; t <= t1; ++t) {
        const int kk0 = t * 64;

        // ---- issue next tile's staging into the other buffer ----
        if (t < t1) {
            gload16(kg0, Kn + wid * 1024);
            gload16(kg1, Kn + wid * 1024 + 512);
            gload16(vg0, Vn + wid * 1024);
            gload16(vg1, Vn + wid * 1024 + 512);
            kg0 += 64 * DD; kg1 += 64 * DD; vg0 += 64; vg1 += 64;
        }

        // ---- QK^T from LDS ----
        f32x4 s[4];
        __builtin_amdgcn_s_setprio(1);
#pragma unroll
        for (int kf = 0; kf < 4; ++kf) {
            bf16x8 ka0 = *(const bf16x8*)(Kc + kf * 1024 + ka_off);
            bf16x8 ka1 = *(const bf16x8*)(Kc + kf * 1024 + (ka_off ^ 32));
            f32x4 z = (f32x4){0.f, 0.f, 0.f, 0.f};
            z = __builtin_amdgcn_mfma_f32_16x16x32_bf16(ka0, qf0, z, 0, 0, 0);
            z = __builtin_amdgcn_mfma_f32_16x16x32_bf16(ka1, qf1, z, 0, 0, 0);
            s[kf] = z;
        }
        __builtin_amdgcn_s_setprio(0);

        // ---- exact mask only on boundary tiles ----
        const bool needmask = !((tq_max - tb[kk0] <= WINDOWF - 4.0f) &&
                                (tb[kk0 + 63] - tq_min <= WINDOWF - 4.0f));
        if (needmask) {
#pragma unroll
            for (int kf = 0; kf < 4; ++kf) {
                float4 tk4 = *(const float4*)(tb + kk0 + kf * 16 + lg * 4);
                if (!(fabsf(tq - tk4.x) <= WINDOWF)) s[kf][0] = -INFINITY;
                if (!(fabsf(tq - tk4.y) <= WINDOWF)) s[kf][1] = -INFINITY;
                if (!(fabsf(tq - tk4.z) <= WINDOWF)) s[kf][2] = -INFINITY;
                if (!(fabsf(tq - tk4.w) <= WINDOWF)) s[kf][3] = -INFINITY;
            }
        }

        // ---- online softmax with defer-max (max via max3 tree) ----
        float t1_ = fmaxf(fmaxf(s[0][0], s[0][1]), s[0][2]);
        float t2_ = fmaxf(fmaxf(s[0][3], s[1][0]), s[1][1]);
        float t3_ = fmaxf(fmaxf(s[1][2], s[1][3]), s[2][0]);
        float t4_ = fmaxf(fmaxf(s[2][1], s[2][2]), s[2][3]);
        float t5_ = fmaxf(fmaxf(s[3][0], s[3][1]), s[3][2]);
        float mt = fmaxf(fmaxf(fmaxf(t1_, t2_), fmaxf(t3_, t4_)),
                         fmaxf(t5_, s[3][3]));
        mt = fmaxf(mt, __shfl_xor(mt, 16));
        mt = fmaxf(mt, __shfl_xor(mt, 32));
        if (!__all(mt <= m_ + 8.0f)) {
            const float mn = fmaxf(m_, mt);
            const float f_ = __builtin_amdgcn_exp2f(m_ - mn);
            l_ *= f_;
#pragma unroll
            for (int df = 0; df < 4; ++df)
#pragma unroll
                for (int r = 0; r < 4; ++r) o_[df][r] *= f_;
            m_ = mn;
        }
        float rs = 0.f;
#pragma unroll
        for (int kf = 0; kf < 4; ++kf)
#pragma unroll
            for (int r = 0; r < 4; ++r) {
                float p = __builtin_amdgcn_exp2f(s[kf][r] - m_);
                s[kf][r] = p;
                rs += p;
            }
        rs += __shfl_xor(rs, 16);
        rs += __shfl_xor(rs, 32);
        l_ += rs;

        // ---- P^T -> packed bf16 (in-register) ----
        union { unsigned int u[4]; bf16x8 v; } pb[2];
#pragma unroll
        for (int c = 0; c < 2; ++c) {
            pb[c].u[0] = cvt_pk_bf16(s[2 * c][0],     s[2 * c][1]);
            pb[c].u[1] = cvt_pk_bf16(s[2 * c][2],     s[2 * c][3]);
            pb[c].u[2] = cvt_pk_bf16(s[2 * c + 1][0], s[2 * c + 1][1]);
            pb[c].u[3] = cvt_pk_bf16(s[2 * c + 1][2], s[2 * c + 1][3]);
        }

        // ---- O^T += V^T . P^T from LDS ----
        __builtin_amdgcn_s_setprio(1);
#pragma unroll
        for (int df = 0; df < 4; ++df) {
            const int base = df * 1024;
            union { bf16x4 hh[2]; bf16x8 v; } va0, va1;
            va0.hh[0] = *(const bf16x4*)(Vc + base + pv0);
            va0.hh[1] = *(const bf16x4*)(Vc + base + pv1);
            va1.hh[0] = *(const bf16x4*)(Vc + base + pv2);
            va1.hh[1] = *(const bf16x4*)(Vc + base + pv3);
            o_[df] = __builtin_amdgcn_mfma_f32_16x16x32_bf16(va0.v, pb[0].v, o_[df], 0, 0, 0);
            o_[df] = __builtin_amdgcn_mfma_f32_16x16x32_bf16(va1.v, pb[1].v, o_[df], 0, 0, 0);
        }
        __builtin_amdgcn_s_setprio(0);

        __syncthreads();     // drains staging vmcnt; all reads of cur done
        unsigned short* tk = Kc; Kc = Kn; Kn = tk;
        unsigned short* tv = Vc; Vc = Vn; Vn = tv;
    }

    // finalize: attended[q][d] = O^T / l, packed 8B stores
    const float inv = 1.f / l_;
#pragma unroll
    for (int df = 0; df < 4; ++df) {
        s16x4 o;
#pragma unroll
        for (int r = 0; r < 4; ++r) o[r] = (short)f2b(o_[df][r] * inv);
        *(s16x4*)(Ab + qrow * DD + h * HDD + df * 16 + lg * 4) = o;
    }
}

// ---------------------------------------------------------------------------
// change_scores[n] = out[n,:] . Wc + bc   (one wave per row)
// ---------------------------------------------------------------------------
__global__ __launch_bounds__(256)
void change_kernel(const float* __restrict__ out, const float* __restrict__ Wc,
                   const float* __restrict__ bc, float* __restrict__ cs)
{
    int row = blockIdx.x * 4 + (threadIdx.x >> 6);
    int lane = threadIdx.x & 63;
    const float* o = out + (size_t)row * DD;
    float sum = 0.f;
#pragma unroll
    for (int k = 0; k < DD / 256; ++k) {
        int c = lane * 4 + k * 256;
        float4 v = *(const float4*)(o + c);
        float4 w = *(const float4*)(Wc + c);
        sum += v.x * w.x + v.y * w.y + v.z * w.z + v.w * w.w;
    }
#pragma unroll
    for (int off = 1; off < 64; off <<= 1) sum += __shfl_xor(sum, off);
    if (lane == 0) cs[row] = sum + bc[0];
}

// ---------------------------------------------------------------------------
extern "C" void kernel_launch(void* const* d_in, const int* in_sizes, int n_in,
                              void* d_out, int out_size, void* d_ws, size_t ws_size,
                              hipStream_t stream)
{
    (void)in_sizes; (void)n_in; (void)out_size; (void)ws_size;
    const float* x  = (const float*)d_in[0];
    const float* ts = (const float*)d_in[1];
    const float* Wq = (const float*)d_in[2];
    const float* bq = (const float*)d_in[3];
    const float* Wk = (const float*)d_in[4];
    const float* bk = (const float*)d_in[5];
    const float* Wv = (const float*)d_in[6];
    const float* bv = (const float*)d_in[7];
    const float* Wo = (const float*)d_in[8];
    const float* bo = (const float*)d_in[9];
    const float* Wc = (const float*)d_in[10];
    const float* bc = (const float*)d_in[11];

    float* out = (float*)d_out;                 // [N*D] output, then [N] change scores

    unsigned short* xb  = (unsigned short*)d_ws;
    unsigned short* Qb  = xb  + (size_t)NN * DD;
    unsigned short* Kb2 = Qb  + (size_t)NN * DD;
    unsigned short* Vtb = Kb2 + (size_t)NN * DD;   // transposed [b][h*64+d][s]
    unsigned short* Abf = Vtb + (size_t)NN * DD;
    unsigned short* Wqb = Abf + (size_t)NN * DD;
    unsigned short* Wkb = Wqb + (size_t)DD * DD;
    unsigned short* Wvb = Wkb + (size_t)DD * DD;
    unsigned short* Wob = Wvb + (size_t)DD * DD;
    int* lo = (int*)(Wob + (size_t)DD * DD);
    int* hi = lo + NN;

    // fused converts + band bounds (one launch)
    cvt_band<<<12320, 256, 0, stream>>>(x, Wq, Wk, Wv, Wo, ts,
                                        xb, Wqb, Wkb, Wvb, Wob, lo, hi);

    // fused Q/K/V projections (one launch)
    gemm_qkv<<<dim3(NN / 128, 24), 256, 0, stream>>>(
        xb, Wqb, Wkb, Wvb, bq, bk, bv, Qb, Kb2, Vtb);

    attn_mfma<<<BB * HH * (SS / 64), 256, 0, stream>>>(Qb, Kb2, Vtb, ts, lo, hi, Abf);
    gemm_wo<<<dim3(NN / 128, DD / 128), 256, 0, stream>>>(Abf, Wob, bo, out);
    change_kernel<<<NN / 4, 256, 0, stream>>>(out, Wc, bc, out + (size_t)NN * DD);
}